// Round 8
// baseline (423.509 us; speedup 1.0000x reference)
//
#include <hip/hip_runtime.h>
#include <cstdint>
#include <cstddef>

#define DD 64

typedef float    f32x4  __attribute__((ext_vector_type(4)));
typedef _Float16 f16x8  __attribute__((ext_vector_type(8)));
typedef _Float16 f16x4  __attribute__((ext_vector_type(4)));

__device__ __forceinline__ float sigmoidf_(float x) {
    return 1.0f / (1.0f + __expf(-x));
}
__device__ __forceinline__ float tanh_fast(float x) {
    float ax = fabsf(x);
    float t = 1.0f - 2.0f / (1.0f + __expf(2.0f * ax));
    return copysignf(t, x);
}
__device__ __forceinline__ f32x4 MFMA(f32x4 c, f16x8 a, f16x8 b) {
    return __builtin_amdgcn_mfma_f32_16x16x32_f16(a, b, c, 0, 0, 0);
}

// ---------------- fused: B-fragment build (blocks 0..15) + winner init ----------------
// B[128][256]: cols 0..63 r (K: x|h), 64..127 z, 128..191 i_n (x), 192..255 h_n (h).
// Fragment f = g*4+s; lane l holds B[s*32+(l>>4)*8+j][g*16+(l&15)], j=0..7.
__global__ void k_prep_init(const float* __restrict__ Wih, const float* __restrict__ Whh,
                            _Float16* __restrict__ bhi, _Float16* __restrict__ blo,
                            int* __restrict__ winner, int num_nodes)
{
    if (blockIdx.x < 16) {
        int f = blockIdx.x * 4 + (threadIdx.x >> 6);   // 0..63
        int l = threadIdx.x & 63;
        int g = f >> 2, s = f & 3;
        int c = g * 16 + (l & 15);
        int grp = c >> 6, dd = c & 63;
        int kbase = s * 32 + (l >> 4) * 8;
        int row = (grp == 0) ? dd : (grp == 1) ? 64 + dd : 128 + dd;

        f16x8 hv, lv;
        for (int j = 0; j < 8; ++j) {
            int k = kbase + j;
            float v;
            if (grp <= 1)      v = (k < 64) ? Wih[row * 64 + k] : Whh[row * 64 + (k - 64)];
            else if (grp == 2) v = (k < 64) ? Wih[row * 64 + k] : 0.0f;
            else               v = (k < 64) ? 0.0f : Whh[row * 64 + (k - 64)];
            _Float16 h = (_Float16)v;
            hv[j] = h;
            lv[j] = (_Float16)(v - (float)h);
        }
        size_t off = ((size_t)f * 64 + l);
        ((f16x8*)bhi)[off] = hv;
        ((f16x8*)blo)[off] = lv;
    } else {
        int i = (int)(blockIdx.x - 16) * 256 + threadIdx.x;
        if (i < num_nodes) winner[i] = -1;
    }
}

__global__ void k_vote(const int* __restrict__ ids, int* __restrict__ winner, int n) {
    int i = blockIdx.x * blockDim.x + threadIdx.x;
    if (i < n) atomicMax(&winner[ids[i]], i);
}

// ---------------- main GRU kernel: 128 events/block, forced 16-load burst ----------------
__global__ __launch_bounds__(256, 3) void k_gru(
    const int* __restrict__ ids,
    const float* __restrict__ emb,
    const float* __restrict__ ts,
    const float* __restrict__ mem,
    const float* __restrict__ lut,
    const float* __restrict__ Wt,
    const float* __restrict__ bt,
    const float* __restrict__ bih,
    const float* __restrict__ bhh,
    const _Float16* __restrict__ bhi,
    const _Float16* __restrict__ blo,
    const int* __restrict__ winner,
    float* __restrict__ out0,
    float* __restrict__ out1,
    int n)
{
    __shared__ _Float16 xhh[64][136];   // [event][k]: k<64 x_hi, k>=64 h
    __shared__ _Float16 xhl[64][72];    // x_lo
    __shared__ int sid[128];
    __shared__ int swin[128];

    const int w    = threadIdx.x >> 6;
    const int l    = threadIdx.x & 63;
    const int col  = l & 15;
    const int rowg = l >> 4;
    const int d    = w * 16 + col;

    // ---- B fragments: issue first (first use = MFMA A; fly under the scalar chase) ----
    const f16x8* H = (const f16x8*)bhi;
    const f16x8* L = (const f16x8*)blo;
    f16x8 BRh0 = H[(size_t)(w * 4 + 0) * 64 + l];
    f16x8 BRh1 = H[(size_t)(w * 4 + 1) * 64 + l];
    f16x8 BRh2 = H[(size_t)(w * 4 + 2) * 64 + l];
    f16x8 BRh3 = H[(size_t)(w * 4 + 3) * 64 + l];
    f16x8 BRl0 = L[(size_t)(w * 4 + 0) * 64 + l];
    f16x8 BRl1 = L[(size_t)(w * 4 + 1) * 64 + l];
    f16x8 BZh0 = H[(size_t)((4 + w) * 4 + 0) * 64 + l];
    f16x8 BZh1 = H[(size_t)((4 + w) * 4 + 1) * 64 + l];
    f16x8 BZh2 = H[(size_t)((4 + w) * 4 + 2) * 64 + l];
    f16x8 BZh3 = H[(size_t)((4 + w) * 4 + 3) * 64 + l];
    f16x8 BZl0 = L[(size_t)((4 + w) * 4 + 0) * 64 + l];
    f16x8 BZl1 = L[(size_t)((4 + w) * 4 + 1) * 64 + l];
    f16x8 BIh0 = H[(size_t)((8 + w) * 4 + 0) * 64 + l];
    f16x8 BIh1 = H[(size_t)((8 + w) * 4 + 1) * 64 + l];
    f16x8 BIl0 = L[(size_t)((8 + w) * 4 + 0) * 64 + l];
    f16x8 BIl1 = L[(size_t)((8 + w) * 4 + 1) * 64 + l];
    f16x8 BHh0 = H[(size_t)((12 + w) * 4 + 2) * 64 + l];
    f16x8 BHh1 = H[(size_t)((12 + w) * 4 + 3) * 64 + l];

    const f32x4 wt4 = ((const f32x4*)Wt)[col];
    const f32x4 bt4 = ((const f32x4*)bt)[col];
    const float bR  = bih[d] + bhh[d];
    const float bZ  = bih[64 + d] + bhh[64 + d];
    const float bIN = bih[128 + d];
    const float bHN = bhh[128 + d];

    const long base = (long)blockIdx.x * 128;
    const bool full = (base + 128 <= (long)n);

    // ---- scalar chase for both chunks (one per 128 events) ----
    const int  e16 = w * 16 + col;
    const long evA = base + e16;
    const long evB = evA + 64;
    int idA = 0, winA = 0, idB = 0, winB = 0;
    float dtA = 0.f, dtB = 0.f;
    if (full || evA < n) {
        idA  = ids[evA];
        dtA  = ts[evA] - lut[idA];
        winA = (winner[idA] == (int)evA) ? 1 : 0;
    }
    if (full || evB < n) {
        idB  = ids[evB];
        dtB  = ts[evB] - lut[idB];
        winB = (winner[idB] == (int)evB) ? 1 : 0;
    }
    if (l < 16) {
        sid[e16]       = idA;  swin[e16]       = winA;
        sid[64 + e16]  = idB;  swin[64 + e16]  = winB;
    }

    // ---- extract per-iteration ids/dts ----
    int ia0 = __shfl(idA, 0 + rowg),  ia1 = __shfl(idA, 4 + rowg);
    int ia2 = __shfl(idA, 8 + rowg),  ia3 = __shfl(idA, 12 + rowg);
    int ib0 = __shfl(idB, 0 + rowg),  ib1 = __shfl(idB, 4 + rowg);
    int ib2 = __shfl(idB, 8 + rowg),  ib3 = __shfl(idB, 12 + rowg);
    float da0 = __shfl(dtA, 0 + rowg), da1 = __shfl(dtA, 4 + rowg);
    float da2 = __shfl(dtA, 8 + rowg), da3 = __shfl(dtA, 12 + rowg);
    float db0 = __shfl(dtB, 0 + rowg), db1 = __shfl(dtB, 4 + rowg);
    float db2 = __shfl(dtB, 8 + rowg), db3 = __shfl(dtB, 12 + rowg);

    // ---- burst: 16 independent 16B loads, pinned before any convert ----
    const f32x4* emb4 = (const f32x4*)emb;
    const f32x4* mem4 = (const f32x4*)mem;
    f32x4 xa0, xa1, xa2, xa3, ha0, ha1, ha2, ha3;
    f32x4 xb0, xb1, xb2, xb3, hb0, hb1, hb2, hb3;
    if (full) {
        xa0 = __builtin_nontemporal_load(&emb4[(size_t)(base + w * 16 + 0 + rowg) * 16 + col]);
        xa1 = __builtin_nontemporal_load(&emb4[(size_t)(base + w * 16 + 4 + rowg) * 16 + col]);
        xa2 = __builtin_nontemporal_load(&emb4[(size_t)(base + w * 16 + 8 + rowg) * 16 + col]);
        xa3 = __builtin_nontemporal_load(&emb4[(size_t)(base + w * 16 + 12 + rowg) * 16 + col]);
        xb0 = __builtin_nontemporal_load(&emb4[(size_t)(base + 64 + w * 16 + 0 + rowg) * 16 + col]);
        xb1 = __builtin_nontemporal_load(&emb4[(size_t)(base + 64 + w * 16 + 4 + rowg) * 16 + col]);
        xb2 = __builtin_nontemporal_load(&emb4[(size_t)(base + 64 + w * 16 + 8 + rowg) * 16 + col]);
        xb3 = __builtin_nontemporal_load(&emb4[(size_t)(base + 64 + w * 16 + 12 + rowg) * 16 + col]);
        ha0 = mem4[(size_t)ia0 * 16 + col];
        ha1 = mem4[(size_t)ia1 * 16 + col];
        ha2 = mem4[(size_t)ia2 * 16 + col];
        ha3 = mem4[(size_t)ia3 * 16 + col];
        hb0 = mem4[(size_t)ib0 * 16 + col];
        hb1 = mem4[(size_t)ib1 * 16 + col];
        hb2 = mem4[(size_t)ib2 * 16 + col];
        hb3 = mem4[(size_t)ib3 * 16 + col];
    } else {
        f32x4 z = {0.f, 0.f, 0.f, 0.f};
        xa0 = xa1 = xa2 = xa3 = ha0 = ha1 = ha2 = ha3 = z;
        xb0 = xb1 = xb2 = xb3 = hb0 = hb1 = hb2 = hb3 = z;
        if (base + w * 16 + 0 + rowg  < n) { xa0 = emb4[(size_t)(base + w * 16 + 0 + rowg) * 16 + col];  ha0 = mem4[(size_t)ia0 * 16 + col]; }
        if (base + w * 16 + 4 + rowg  < n) { xa1 = emb4[(size_t)(base + w * 16 + 4 + rowg) * 16 + col];  ha1 = mem4[(size_t)ia1 * 16 + col]; }
        if (base + w * 16 + 8 + rowg  < n) { xa2 = emb4[(size_t)(base + w * 16 + 8 + rowg) * 16 + col];  ha2 = mem4[(size_t)ia2 * 16 + col]; }
        if (base + w * 16 + 12 + rowg < n) { xa3 = emb4[(size_t)(base + w * 16 + 12 + rowg) * 16 + col]; ha3 = mem4[(size_t)ia3 * 16 + col]; }
        if (base + 64 + w * 16 + 0 + rowg  < n) { xb0 = emb4[(size_t)(base + 64 + w * 16 + 0 + rowg) * 16 + col];  hb0 = mem4[(size_t)ib0 * 16 + col]; }
        if (base + 64 + w * 16 + 4 + rowg  < n) { xb1 = emb4[(size_t)(base + 64 + w * 16 + 4 + rowg) * 16 + col];  hb1 = mem4[(size_t)ib1 * 16 + col]; }
        if (base + 64 + w * 16 + 8 + rowg  < n) { xb2 = emb4[(size_t)(base + 64 + w * 16 + 8 + rowg) * 16 + col];  hb2 = mem4[(size_t)ib2 * 16 + col]; }
        if (base + 64 + w * 16 + 12 + rowg < n) { xb3 = emb4[(size_t)(base + 64 + w * 16 + 12 + rowg) * 16 + col]; hb3 = mem4[(size_t)ib3 * 16 + col]; }
    }
    __builtin_amdgcn_sched_barrier(0);   // loads stay issued before converts

    #define CONV_WRITE(XV, HV, DT, IT)                                           \
    {                                                                            \
        int r = w * 16 + (IT) * 4 + rowg;                                        \
        f32x4 x = XV;                                                            \
        x.x = fmaf(DT, wt4.x, x.x + bt4.x);                                      \
        x.y = fmaf(DT, wt4.y, x.y + bt4.y);                                      \
        x.z = fmaf(DT, wt4.z, x.z + bt4.z);                                      \
        x.w = fmaf(DT, wt4.w, x.w + bt4.w);                                      \
        f16x4 xh, xl, hh;                                                        \
        _Float16 a;                                                              \
        a = (_Float16)x.x; xh[0] = a; xl[0] = (_Float16)(x.x - (float)a);        \
        a = (_Float16)x.y; xh[1] = a; xl[1] = (_Float16)(x.y - (float)a);        \
        a = (_Float16)x.z; xh[2] = a; xl[2] = (_Float16)(x.z - (float)a);        \
        a = (_Float16)x.w; xh[3] = a; xl[3] = (_Float16)(x.w - (float)a);        \
        hh[0] = (_Float16)(HV).x; hh[1] = (_Float16)(HV).y;                      \
        hh[2] = (_Float16)(HV).z; hh[3] = (_Float16)(HV).w;                      \
        *(f16x4*)&xhh[r][col * 4]      = xh;                                     \
        *(f16x4*)&xhl[r][col * 4]      = xl;                                     \
        *(f16x4*)&xhh[r][64 + col * 4] = hh;                                     \
    }

    #define DO_MFMA_EPI(CB)                                                      \
    {                                                                            \
        _Pragma("unroll")                                                        \
        for (int mt = 0; mt < 4; ++mt) {                                         \
            const int arow = mt * 16 + col;                                      \
            const int k0   = rowg * 8;                                           \
            f16x8 Ah0 = *(const f16x8*)&xhh[arow][0 * 32 + k0];                  \
            f16x8 Ah1 = *(const f16x8*)&xhh[arow][1 * 32 + k0];                  \
            f16x8 Ah2 = *(const f16x8*)&xhh[arow][2 * 32 + k0];                  \
            f16x8 Ah3 = *(const f16x8*)&xhh[arow][3 * 32 + k0];                  \
            f16x8 Al0 = *(const f16x8*)&xhl[arow][0 * 32 + k0];                  \
            f16x8 Al1 = *(const f16x8*)&xhl[arow][1 * 32 + k0];                  \
            f32x4 aR = {0,0,0,0}, aZ = {0,0,0,0}, aI = {0,0,0,0}, aH = {0,0,0,0};\
            __builtin_amdgcn_s_setprio(1);                                       \
            aR = MFMA(aR, Ah0, BRh0); aR = MFMA(aR, Ah0, BRl0);                  \
            aR = MFMA(aR, Al0, BRh0); aR = MFMA(aR, Ah1, BRh1);                  \
            aR = MFMA(aR, Ah1, BRl1); aR = MFMA(aR, Al1, BRh1);                  \
            aR = MFMA(aR, Ah2, BRh2); aR = MFMA(aR, Ah3, BRh3);                  \
            aZ = MFMA(aZ, Ah0, BZh0); aZ = MFMA(aZ, Ah0, BZl0);                  \
            aZ = MFMA(aZ, Al0, BZh0); aZ = MFMA(aZ, Ah1, BZh1);                  \
            aZ = MFMA(aZ, Ah1, BZl1); aZ = MFMA(aZ, Al1, BZh1);                  \
            aZ = MFMA(aZ, Ah2, BZh2); aZ = MFMA(aZ, Ah3, BZh3);                  \
            aI = MFMA(aI, Ah0, BIh0); aI = MFMA(aI, Ah0, BIl0);                  \
            aI = MFMA(aI, Al0, BIh0); aI = MFMA(aI, Ah1, BIh1);                  \
            aI = MFMA(aI, Ah1, BIl1); aI = MFMA(aI, Al1, BIh1);                  \
            aH = MFMA(aH, Ah2, BHh0); aH = MFMA(aH, Ah3, BHh1);                  \
            __builtin_amdgcn_s_setprio(0);                                       \
            _Pragma("unroll")                                                    \
            for (int r = 0; r < 4; ++r) {                                        \
                int  eloc = mt * 16 + rowg * 4 + r;                              \
                long ev   = base + (CB) + eloc;                                  \
                if (full || ev < n) {                                            \
                    float rr = sigmoidf_(aR[r] + bR);                            \
                    float zz = sigmoidf_(aZ[r] + bZ);                            \
                    float nn = tanh_fast(aI[r] + bIN + rr * (aH[r] + bHN));      \
                    float hv = (float)xhh[eloc][64 + d];                         \
                    float o  = (1.f - zz) * nn + zz * hv;                        \
                    __builtin_nontemporal_store(o, &out0[(size_t)ev * 64 + d]);  \
                    if (swin[(CB) + eloc])                                       \
                        __builtin_nontemporal_store(o, &out1[(size_t)sid[(CB) + eloc] * 64 + d]); \
                }                                                                \
            }                                                                    \
        }                                                                        \
    }

    // ---- chunk A ----
    CONV_WRITE(xa0, ha0, da0, 0)
    CONV_WRITE(xa1, ha1, da1, 1)
    CONV_WRITE(xa2, ha2, da2, 2)
    CONV_WRITE(xa3, ha3, da3, 3)
    __syncthreads();
    DO_MFMA_EPI(0)
    __syncthreads();

    // ---- chunk B (reuse LDS) ----
    CONV_WRITE(xb0, hb0, db0, 0)
    CONV_WRITE(xb1, hb1, db1, 1)
    CONV_WRITE(xb2, hb2, db2, 2)
    CONV_WRITE(xb3, hb3, db3, 3)
    __syncthreads();
    DO_MFMA_EPI(64)

    #undef CONV_WRITE
    #undef DO_MFMA_EPI
}

// ---------------- fused tail: loser-row copy + timestamp scatter (4 thr/node) ----------------
__global__ void k_tail(float* out2,
                       const f32x4* __restrict__ mem4,
                       f32x4* __restrict__ out14,
                       const float* __restrict__ ts,
                       const float* __restrict__ lut,
                       int num_nodes)
{
    int idx  = blockIdx.x * blockDim.x + threadIdx.x;
    int node = idx >> 2;
    int q    = idx & 3;
    if (node >= num_nodes) return;
    int wv = reinterpret_cast<const int*>(out2)[node];
    if (wv < 0) {
        size_t o = (size_t)node * 16 + q * 4;
        f32x4 v0 = __builtin_nontemporal_load(&mem4[o + 0]);
        f32x4 v1 = __builtin_nontemporal_load(&mem4[o + 1]);
        f32x4 v2 = __builtin_nontemporal_load(&mem4[o + 2]);
        f32x4 v3 = __builtin_nontemporal_load(&mem4[o + 3]);
        __builtin_nontemporal_store(v0, &out14[o + 0]);
        __builtin_nontemporal_store(v1, &out14[o + 1]);
        __builtin_nontemporal_store(v2, &out14[o + 2]);
        __builtin_nontemporal_store(v3, &out14[o + 3]);
    }
    if (q == 0) out2[node] = (wv >= 0) ? ts[wv] : lut[node];
}

extern "C" void kernel_launch(void* const* d_in, const int* in_sizes, int n_in,
                              void* d_out, int out_size, void* d_ws, size_t ws_size,
                              hipStream_t stream) {
    const int*   ids = (const int*)  d_in[0];
    const float* emb = (const float*)d_in[1];
    const float* ts  = (const float*)d_in[2];
    const float* mem = (const float*)d_in[3];
    const float* lut = (const float*)d_in[4];
    const float* Wt  = (const float*)d_in[5];
    const float* bt  = (const float*)d_in[6];
    const float* Wih = (const float*)d_in[7];
    const float* Whh = (const float*)d_in[8];
    const float* bih = (const float*)d_in[9];
    const float* bhh = (const float*)d_in[10];

    const int N         = in_sizes[0];
    const int NUM_NODES = in_sizes[4];

    float* out0 = (float*)d_out;                    // [N,64]
    float* out1 = out0 + (size_t)N * DD;            // [NUM_NODES,64]
    float* out2 = out1 + (size_t)NUM_NODES * DD;    // [NUM_NODES]
    int*   winner = (int*)out2;

    _Float16* bfragH = (_Float16*)d_ws;             // 64 KB
    _Float16* bfragL = bfragH + 64 * 64 * 8;        // 64 KB

    int initBlocks = (NUM_NODES + 255) / 256;
    k_prep_init<<<16 + initBlocks, 256, 0, stream>>>(Wih, Whh, bfragH, bfragL,
                                                     winner, NUM_NODES);
    k_vote<<<(N + 255) / 256, 256, 0, stream>>>(ids, winner, N);

    int gruBlocks = (N + 127) / 128;
    k_gru<<<gruBlocks, 256, 0, stream>>>(ids, emb, ts, mem, lut, Wt, bt, bih, bhh,
                                         bfragH, bfragL, winner, out0, out1, N);

    long tailThreads = (long)NUM_NODES * 4;
    k_tail<<<(int)((tailThreads + 255) / 256), 256, 0, stream>>>(
        out2, (const f32x4*)mem, (f32x4*)out1, ts, lut, NUM_NODES);
}

// Round 9
// 375.819 us; speedup vs baseline: 1.1269x; 1.1269x over previous
//
#include <hip/hip_runtime.h>
#include <cstdint>
#include <cstddef>

#define DD 64

typedef float    f32x4  __attribute__((ext_vector_type(4)));
typedef _Float16 f16x8  __attribute__((ext_vector_type(8)));
typedef _Float16 f16x4  __attribute__((ext_vector_type(4)));

__device__ __forceinline__ float sigmoidf_(float x) {
    return 1.0f / (1.0f + __expf(-x));
}
__device__ __forceinline__ float tanh_fast(float x) {
    float ax = fabsf(x);
    float t = 1.0f - 2.0f / (1.0f + __expf(2.0f * ax));
    return copysignf(t, x);
}
__device__ __forceinline__ f32x4 MFMA(f32x4 c, f16x8 a, f16x8 b) {
    return __builtin_amdgcn_mfma_f32_16x16x32_f16(a, b, c, 0, 0, 0);
}
// async global->LDS, 16B per lane; dest = wave-uniform base + lane*16
__device__ __forceinline__ void gl2lds16(const void* g, void* l) {
    __builtin_amdgcn_global_load_lds(
        (const __attribute__((address_space(1))) void*)g,
        (__attribute__((address_space(3))) void*)l,
        16, 0, 0);
}

// ---------------- fused: B-fragment build (blocks 0..15) + winner init ----------------
// B[128][256]: cols 0..63 r (K: x|h), 64..127 z, 128..191 i_n (x), 192..255 h_n (h).
// Fragment f = g*4+s; lane l holds B[s*32+(l>>4)*8+j][g*16+(l&15)], j=0..7.
__global__ void k_prep_init(const float* __restrict__ Wih, const float* __restrict__ Whh,
                            _Float16* __restrict__ bhi, _Float16* __restrict__ blo,
                            int* __restrict__ winner, int num_nodes)
{
    if (blockIdx.x < 16) {
        int f = blockIdx.x * 4 + (threadIdx.x >> 6);   // 0..63
        int l = threadIdx.x & 63;
        int g = f >> 2, s = f & 3;
        int c = g * 16 + (l & 15);
        int grp = c >> 6, dd = c & 63;
        int kbase = s * 32 + (l >> 4) * 8;
        int row = (grp == 0) ? dd : (grp == 1) ? 64 + dd : 128 + dd;

        f16x8 hv, lv;
        for (int j = 0; j < 8; ++j) {
            int k = kbase + j;
            float v;
            if (grp <= 1)      v = (k < 64) ? Wih[row * 64 + k] : Whh[row * 64 + (k - 64)];
            else if (grp == 2) v = (k < 64) ? Wih[row * 64 + k] : 0.0f;
            else               v = (k < 64) ? 0.0f : Whh[row * 64 + (k - 64)];
            _Float16 h = (_Float16)v;
            hv[j] = h;
            lv[j] = (_Float16)(v - (float)h);
        }
        size_t off = ((size_t)f * 64 + l);
        ((f16x8*)bhi)[off] = hv;
        ((f16x8*)blo)[off] = lv;
    } else {
        int i = (int)(blockIdx.x - 16) * 256 + threadIdx.x;
        if (i < num_nodes) winner[i] = -1;
    }
}

__global__ void k_vote(const int* __restrict__ ids, int* __restrict__ winner, int n) {
    int i = blockIdx.x * blockDim.x + threadIdx.x;
    if (i < n) atomicMax(&winner[ids[i]], i);
}

// ---------------- main GRU kernel: global_load_lds burst staging ----------------
// 64 events/block. Raw f32 x/h staged async into LDS (zero registers held),
// then converted to fp16 fragment planes (x split hi/lo, h plain).
__global__ __launch_bounds__(256, 3) void k_gru(
    const int* __restrict__ ids,
    const float* __restrict__ emb,
    const float* __restrict__ ts,
    const float* __restrict__ mem,
    const float* __restrict__ lut,
    const float* __restrict__ Wt,
    const float* __restrict__ bt,
    const float* __restrict__ bih,
    const float* __restrict__ bhh,
    const _Float16* __restrict__ bhi,
    const _Float16* __restrict__ blo,
    const int* __restrict__ winner,
    float* __restrict__ out0,
    float* __restrict__ out1,
    int n)
{
    __shared__ __align__(16) union {
        struct { float x[64][64]; float h[64][64]; } raw;              // 32 KB
        struct { _Float16 hh[64][136]; _Float16 hl[64][72]; } fr;      // 26.6 KB
    } u;
    __shared__ int sid[64];
    __shared__ int swin[64];

    const int w    = threadIdx.x >> 6;
    const int l    = threadIdx.x & 63;
    const int col  = l & 15;
    const int rowg = l >> 4;
    const int d    = w * 16 + col;

    const long base = (long)blockIdx.x * 64;
    const bool full = (base + 64 <= (long)n);

    // ---- issue emb gloads first: no deps, fly under the scalar chase ----
    if (full) {
        gl2lds16(emb + (size_t)(base + w * 16 + 0  + rowg) * 64 + col * 4, &u.raw.x[w * 16 + 0][0]);
        gl2lds16(emb + (size_t)(base + w * 16 + 4  + rowg) * 64 + col * 4, &u.raw.x[w * 16 + 4][0]);
        gl2lds16(emb + (size_t)(base + w * 16 + 8  + rowg) * 64 + col * 4, &u.raw.x[w * 16 + 8][0]);
        gl2lds16(emb + (size_t)(base + w * 16 + 12 + rowg) * 64 + col * 4, &u.raw.x[w * 16 + 12][0]);
    }

    // ---- scalar chase: all lanes (mod-16 aliasing shares cache lines) ----
    const int  e16 = w * 16 + col;
    const long evA = base + e16;
    int idA = 0, winA = 0; float dtA = 0.f;
    if (full || evA < n) {
        idA  = ids[evA];
        dtA  = ts[evA] - lut[idA];
        winA = (winner[idA] == (int)evA) ? 1 : 0;
    }

    int ia0 = __shfl(idA, 0 + rowg),  ia1 = __shfl(idA, 4 + rowg);
    int ia2 = __shfl(idA, 8 + rowg),  ia3 = __shfl(idA, 12 + rowg);
    float da0 = __shfl(dtA, 0 + rowg), da1 = __shfl(dtA, 4 + rowg);
    float da2 = __shfl(dtA, 8 + rowg), da3 = __shfl(dtA, 12 + rowg);

    // ---- issue mem gathers (per-lane global src, linear LDS dest) ----
    if (full) {
        gl2lds16(mem + (size_t)ia0 * 64 + col * 4, &u.raw.h[w * 16 + 0][0]);
        gl2lds16(mem + (size_t)ia1 * 64 + col * 4, &u.raw.h[w * 16 + 4][0]);
        gl2lds16(mem + (size_t)ia2 * 64 + col * 4, &u.raw.h[w * 16 + 8][0]);
        gl2lds16(mem + (size_t)ia3 * 64 + col * 4, &u.raw.h[w * 16 + 12][0]);
    } else {
        #pragma unroll
        for (int it = 0; it < 4; ++it) {
            int  r  = w * 16 + it * 4 + rowg;
            long ev = base + r;
            int idt = __shfl(idA, it * 4 + rowg);
            f32x4 xv = {0.f, 0.f, 0.f, 0.f};
            f32x4 hv = {0.f, 0.f, 0.f, 0.f};
            if (ev < n) {
                xv = ((const f32x4*)emb)[(size_t)ev * 16 + col];
                hv = ((const f32x4*)mem)[(size_t)idt * 16 + col];
            }
            *(f32x4*)&u.raw.x[r][col * 4] = xv;
            *(f32x4*)&u.raw.h[r][col * 4] = hv;
        }
    }

    if (l < 16) { sid[e16] = idA; swin[e16] = winA; }

    // ---- B fragments (L2-resident; consumed after 2 barriers) ----
    const f16x8* H = (const f16x8*)bhi;
    const f16x8* L = (const f16x8*)blo;
    f16x8 BRh0 = H[(size_t)(w * 4 + 0) * 64 + l];
    f16x8 BRh1 = H[(size_t)(w * 4 + 1) * 64 + l];
    f16x8 BRh2 = H[(size_t)(w * 4 + 2) * 64 + l];
    f16x8 BRh3 = H[(size_t)(w * 4 + 3) * 64 + l];
    f16x8 BRl0 = L[(size_t)(w * 4 + 0) * 64 + l];
    f16x8 BRl1 = L[(size_t)(w * 4 + 1) * 64 + l];
    f16x8 BZh0 = H[(size_t)((4 + w) * 4 + 0) * 64 + l];
    f16x8 BZh1 = H[(size_t)((4 + w) * 4 + 1) * 64 + l];
    f16x8 BZh2 = H[(size_t)((4 + w) * 4 + 2) * 64 + l];
    f16x8 BZh3 = H[(size_t)((4 + w) * 4 + 3) * 64 + l];
    f16x8 BZl0 = L[(size_t)((4 + w) * 4 + 0) * 64 + l];
    f16x8 BZl1 = L[(size_t)((4 + w) * 4 + 1) * 64 + l];
    f16x8 BIh0 = H[(size_t)((8 + w) * 4 + 0) * 64 + l];
    f16x8 BIh1 = H[(size_t)((8 + w) * 4 + 1) * 64 + l];
    f16x8 BIl0 = L[(size_t)((8 + w) * 4 + 0) * 64 + l];
    f16x8 BIl1 = L[(size_t)((8 + w) * 4 + 1) * 64 + l];
    f16x8 BHh0 = H[(size_t)((12 + w) * 4 + 2) * 64 + l];
    f16x8 BHh1 = H[(size_t)((12 + w) * 4 + 3) * 64 + l];

    const f32x4 wt4 = ((const f32x4*)Wt)[col];
    const f32x4 bt4 = ((const f32x4*)bt)[col];
    const float bR  = bih[d] + bhh[d];
    const float bZ  = bih[64 + d] + bhh[64 + d];
    const float bIN = bih[128 + d];
    const float bHN = bhh[128 + d];

    __syncthreads();   // drains vmcnt: all gload_lds landed

    // ---- phase2a: raw f32 -> regs (wave-local rows) ----
    f32x4 x0 = *(const f32x4*)&u.raw.x[w * 16 + 0  + rowg][col * 4];
    f32x4 x1 = *(const f32x4*)&u.raw.x[w * 16 + 4  + rowg][col * 4];
    f32x4 x2 = *(const f32x4*)&u.raw.x[w * 16 + 8  + rowg][col * 4];
    f32x4 x3 = *(const f32x4*)&u.raw.x[w * 16 + 12 + rowg][col * 4];
    f32x4 h0 = *(const f32x4*)&u.raw.h[w * 16 + 0  + rowg][col * 4];
    f32x4 h1 = *(const f32x4*)&u.raw.h[w * 16 + 4  + rowg][col * 4];
    f32x4 h2 = *(const f32x4*)&u.raw.h[w * 16 + 8  + rowg][col * 4];
    f32x4 h3 = *(const f32x4*)&u.raw.h[w * 16 + 12 + rowg][col * 4];

    __syncthreads();   // all raw reads done before fragment writes alias them

    // ---- phase2b: convert + fragment-plane writes ----
    #define CONV_WRITE(XV, HV, DT, IT)                                           \
    {                                                                            \
        int r = w * 16 + (IT) * 4 + rowg;                                        \
        f32x4 x = XV;                                                            \
        x.x = fmaf(DT, wt4.x, x.x + bt4.x);                                      \
        x.y = fmaf(DT, wt4.y, x.y + bt4.y);                                      \
        x.z = fmaf(DT, wt4.z, x.z + bt4.z);                                      \
        x.w = fmaf(DT, wt4.w, x.w + bt4.w);                                      \
        f16x4 xh, xl, hh;                                                        \
        _Float16 a;                                                              \
        a = (_Float16)x.x; xh[0] = a; xl[0] = (_Float16)(x.x - (float)a);        \
        a = (_Float16)x.y; xh[1] = a; xl[1] = (_Float16)(x.y - (float)a);        \
        a = (_Float16)x.z; xh[2] = a; xl[2] = (_Float16)(x.z - (float)a);        \
        a = (_Float16)x.w; xh[3] = a; xl[3] = (_Float16)(x.w - (float)a);        \
        hh[0] = (_Float16)(HV).x; hh[1] = (_Float16)(HV).y;                      \
        hh[2] = (_Float16)(HV).z; hh[3] = (_Float16)(HV).w;                      \
        *(f16x4*)&u.fr.hh[r][col * 4]      = xh;                                 \
        *(f16x4*)&u.fr.hl[r][col * 4]      = xl;                                 \
        *(f16x4*)&u.fr.hh[r][64 + col * 4] = hh;                                 \
    }
    CONV_WRITE(x0, h0, da0, 0)
    CONV_WRITE(x1, h1, da1, 1)
    CONV_WRITE(x2, h2, da2, 2)
    CONV_WRITE(x3, h3, da3, 3)
    #undef CONV_WRITE

    __syncthreads();

    // ---- 4 M-tiles of 16 events each ----
    #pragma unroll
    for (int mt = 0; mt < 4; ++mt) {
        const int arow = mt * 16 + col;
        const int k0   = rowg * 8;
        f16x8 Ah0 = *(const f16x8*)&u.fr.hh[arow][0 * 32 + k0];
        f16x8 Ah1 = *(const f16x8*)&u.fr.hh[arow][1 * 32 + k0];
        f16x8 Ah2 = *(const f16x8*)&u.fr.hh[arow][2 * 32 + k0];
        f16x8 Ah3 = *(const f16x8*)&u.fr.hh[arow][3 * 32 + k0];
        f16x8 Al0 = *(const f16x8*)&u.fr.hl[arow][0 * 32 + k0];
        f16x8 Al1 = *(const f16x8*)&u.fr.hl[arow][1 * 32 + k0];

        f32x4 aR = {0,0,0,0}, aZ = {0,0,0,0}, aI = {0,0,0,0}, aH = {0,0,0,0};
        __builtin_amdgcn_s_setprio(1);
        aR = MFMA(aR, Ah0, BRh0); aR = MFMA(aR, Ah0, BRl0); aR = MFMA(aR, Al0, BRh0);
        aR = MFMA(aR, Ah1, BRh1); aR = MFMA(aR, Ah1, BRl1); aR = MFMA(aR, Al1, BRh1);
        aR = MFMA(aR, Ah2, BRh2); aR = MFMA(aR, Ah3, BRh3);
        aZ = MFMA(aZ, Ah0, BZh0); aZ = MFMA(aZ, Ah0, BZl0); aZ = MFMA(aZ, Al0, BZh0);
        aZ = MFMA(aZ, Ah1, BZh1); aZ = MFMA(aZ, Ah1, BZl1); aZ = MFMA(aZ, Al1, BZh1);
        aZ = MFMA(aZ, Ah2, BZh2); aZ = MFMA(aZ, Ah3, BZh3);
        aI = MFMA(aI, Ah0, BIh0); aI = MFMA(aI, Ah0, BIl0); aI = MFMA(aI, Al0, BIh0);
        aI = MFMA(aI, Ah1, BIh1); aI = MFMA(aI, Ah1, BIl1); aI = MFMA(aI, Al1, BIh1);
        aH = MFMA(aH, Ah2, BHh0); aH = MFMA(aH, Ah3, BHh1);
        __builtin_amdgcn_s_setprio(0);

        #pragma unroll
        for (int r = 0; r < 4; ++r) {
            int  eloc = mt * 16 + rowg * 4 + r;
            long ev   = base + eloc;
            if (full || ev < n) {
                float rr = sigmoidf_(aR[r] + bR);
                float zz = sigmoidf_(aZ[r] + bZ);
                float nn = tanh_fast(aI[r] + bIN + rr * (aH[r] + bHN));
                float hv = (float)u.fr.hh[eloc][64 + d];
                float o  = (1.f - zz) * nn + zz * hv;
                __builtin_nontemporal_store(o, &out0[(size_t)ev * 64 + d]);
                if (swin[eloc])
                    __builtin_nontemporal_store(o, &out1[(size_t)sid[eloc] * 64 + d]);
            }
        }
    }
}

// ---------------- fused tail: loser-row copy + timestamp scatter (4 thr/node) ----------------
__global__ void k_tail(float* out2,
                       const f32x4* __restrict__ mem4,
                       f32x4* __restrict__ out14,
                       const float* __restrict__ ts,
                       const float* __restrict__ lut,
                       int num_nodes)
{
    int idx  = blockIdx.x * blockDim.x + threadIdx.x;
    int node = idx >> 2;
    int q    = idx & 3;
    if (node >= num_nodes) return;
    int wv = reinterpret_cast<const int*>(out2)[node];
    if (wv < 0) {
        size_t o = (size_t)node * 16 + q * 4;
        f32x4 v0 = __builtin_nontemporal_load(&mem4[o + 0]);
        f32x4 v1 = __builtin_nontemporal_load(&mem4[o + 1]);
        f32x4 v2 = __builtin_nontemporal_load(&mem4[o + 2]);
        f32x4 v3 = __builtin_nontemporal_load(&mem4[o + 3]);
        __builtin_nontemporal_store(v0, &out14[o + 0]);
        __builtin_nontemporal_store(v1, &out14[o + 1]);
        __builtin_nontemporal_store(v2, &out14[o + 2]);
        __builtin_nontemporal_store(v3, &out14[o + 3]);
    }
    if (q == 0) out2[node] = (wv >= 0) ? ts[wv] : lut[node];
}

extern "C" void kernel_launch(void* const* d_in, const int* in_sizes, int n_in,
                              void* d_out, int out_size, void* d_ws, size_t ws_size,
                              hipStream_t stream) {
    const int*   ids = (const int*)  d_in[0];
    const float* emb = (const float*)d_in[1];
    const float* ts  = (const float*)d_in[2];
    const float* mem = (const float*)d_in[3];
    const float* lut = (const float*)d_in[4];
    const float* Wt  = (const float*)d_in[5];
    const float* bt  = (const float*)d_in[6];
    const float* Wih = (const float*)d_in[7];
    const float* Whh = (const float*)d_in[8];
    const float* bih = (const float*)d_in[9];
    const float* bhh = (const float*)d_in[10];

    const int N         = in_sizes[0];
    const int NUM_NODES = in_sizes[4];

    float* out0 = (float*)d_out;                    // [N,64]
    float* out1 = out0 + (size_t)N * DD;            // [NUM_NODES,64]
    float* out2 = out1 + (size_t)NUM_NODES * DD;    // [NUM_NODES]
    int*   winner = (int*)out2;

    _Float16* bfragH = (_Float16*)d_ws;             // 64 KB
    _Float16* bfragL = bfragH + 64 * 64 * 8;        // 64 KB

    int initBlocks = (NUM_NODES + 255) / 256;
    k_prep_init<<<16 + initBlocks, 256, 0, stream>>>(Wih, Whh, bfragH, bfragL,
                                                     winner, NUM_NODES);
    k_vote<<<(N + 255) / 256, 256, 0, stream>>>(ids, winner, N);

    int gruBlocks = (N + 63) / 64;
    k_gru<<<gruBlocks, 256, 0, stream>>>(ids, emb, ts, mem, lut, Wt, bt, bih, bhh,
                                         bfragH, bfragL, winner, out0, out1, N);

    long tailThreads = (long)NUM_NODES * 4;
    k_tail<<<(int)((tailThreads + 255) / 256), 256, 0, stream>>>(
        out2, (const f32x4*)mem, (f32x4*)out1, ts, lut, NUM_NODES);
}

// Round 10
// 290.008 us; speedup vs baseline: 1.4603x; 1.2959x over previous
//
#include <hip/hip_runtime.h>
#include <cstdint>
#include <cstddef>

#define DD 64

typedef float    f32x4  __attribute__((ext_vector_type(4)));
typedef _Float16 f16x8  __attribute__((ext_vector_type(8)));
typedef _Float16 f16x4  __attribute__((ext_vector_type(4)));

__device__ __forceinline__ float sigmoidf_(float x) {
    return 1.0f / (1.0f + __expf(-x));
}
__device__ __forceinline__ float tanh_fast(float x) {
    float ax = fabsf(x);
    float t = 1.0f - 2.0f / (1.0f + __expf(2.0f * ax));
    return copysignf(t, x);
}
__device__ __forceinline__ f32x4 MFMA(f32x4 c, f16x8 a, f16x8 b) {
    return __builtin_amdgcn_mfma_f32_16x16x32_f16(a, b, c, 0, 0, 0);
}

// ---------------- fused: B-fragment build (blocks 0..15) + winner init (ws) ----------------
// B[128][256]: cols 0..63 r (K: x|h), 64..127 z, 128..191 i_n (x), 192..255 h_n (h).
// Fragment f = g*4+s; lane l holds B[s*32+(l>>4)*8+j][g*16+(l&15)], j=0..7.
__global__ void k_prep_init(const float* __restrict__ Wih, const float* __restrict__ Whh,
                            _Float16* __restrict__ bhi, _Float16* __restrict__ blo,
                            int* __restrict__ winner, int num_nodes)
{
    if (blockIdx.x < 16) {
        int f = blockIdx.x * 4 + (threadIdx.x >> 6);   // 0..63
        int l = threadIdx.x & 63;
        int g = f >> 2, s = f & 3;
        int c = g * 16 + (l & 15);
        int grp = c >> 6, dd = c & 63;
        int kbase = s * 32 + (l >> 4) * 8;
        int row = (grp == 0) ? dd : (grp == 1) ? 64 + dd : 128 + dd;

        f16x8 hv, lv;
        for (int j = 0; j < 8; ++j) {
            int k = kbase + j;
            float v;
            if (grp <= 1)      v = (k < 64) ? Wih[row * 64 + k] : Whh[row * 64 + (k - 64)];
            else if (grp == 2) v = (k < 64) ? Wih[row * 64 + k] : 0.0f;
            else               v = (k < 64) ? 0.0f : Whh[row * 64 + (k - 64)];
            _Float16 h = (_Float16)v;
            hv[j] = h;
            lv[j] = (_Float16)(v - (float)h);
        }
        size_t off = ((size_t)f * 64 + l);
        ((f16x8*)bhi)[off] = hv;
        ((f16x8*)blo)[off] = lv;
    } else {
        int i = (int)(blockIdx.x - 16) * 256 + threadIdx.x;
        if (i < num_nodes) winner[i] = -1;
    }
}

__global__ void k_vote(const int* __restrict__ ids, int* __restrict__ winner, int n) {
    int i = blockIdx.x * blockDim.x + threadIdx.x;
    if (i < n) atomicMax(&winner[ids[i]], i);
}

// ---------------- fused main: GRU blocks (idx%3==0) + tail blocks (else) ----------------
// GRU: r7 structure — 64 events/block, wave-private T14 staging, asymmetric split-fp16.
// Tail: loser-row copy + timestamp scatter; interleaved so its BW-bound traffic
// fills the GRU blocks' latency bubbles. winner lives in d_ws -> no out2 hazard.
__global__ __launch_bounds__(256, 3) void k_main(
    const int* __restrict__ ids,
    const float* __restrict__ emb,
    const float* __restrict__ ts,
    const float* __restrict__ mem,
    const float* __restrict__ lut,
    const float* __restrict__ Wt,
    const float* __restrict__ bt,
    const float* __restrict__ bih,
    const float* __restrict__ bhh,
    const _Float16* __restrict__ bhi,
    const _Float16* __restrict__ blo,
    const int* __restrict__ winner,
    float* __restrict__ out0,
    float* __restrict__ out1,
    float* __restrict__ out2,
    int n, int num_nodes)
{
    __shared__ _Float16 xhh[64][136];   // [event][k]: k<64 x_hi, k>=64 h
    __shared__ _Float16 xhl[64][72];    // x_lo
    __shared__ int sid[64];
    __shared__ int swin[64];

    const unsigned bt3 = blockIdx.x % 3;
    if (bt3 != 0) {
        // ---------------- tail block: 64 nodes, 4 threads/node ----------------
        int tail_idx = 2 * (int)(blockIdx.x / 3) + ((int)bt3 - 1);
        int node = tail_idx * 64 + ((int)threadIdx.x >> 2);
        if (node >= num_nodes) return;
        int q  = (int)threadIdx.x & 3;
        int wv = winner[node];
        if (wv < 0) {
            const f32x4* mem4  = (const f32x4*)mem;
            f32x4*       out14 = (f32x4*)out1;
            size_t o = (size_t)node * 16 + q * 4;
            f32x4 v0 = __builtin_nontemporal_load(&mem4[o + 0]);
            f32x4 v1 = __builtin_nontemporal_load(&mem4[o + 1]);
            f32x4 v2 = __builtin_nontemporal_load(&mem4[o + 2]);
            f32x4 v3 = __builtin_nontemporal_load(&mem4[o + 3]);
            __builtin_nontemporal_store(v0, &out14[o + 0]);
            __builtin_nontemporal_store(v1, &out14[o + 1]);
            __builtin_nontemporal_store(v2, &out14[o + 2]);
            __builtin_nontemporal_store(v3, &out14[o + 3]);
        }
        if (q == 0) out2[node] = (wv >= 0) ? ts[wv] : lut[node];
        return;
    }

    // ---------------- GRU block ----------------
    const int w    = threadIdx.x >> 6;
    const int l    = threadIdx.x & 63;
    const int col  = l & 15;
    const int rowg = l >> 4;
    const int d    = w * 16 + col;

    const long base = (long)(blockIdx.x / 3) * 64;
    const bool full = (base + 64 <= (long)n);

    // ---- phase A: every lane loads its event's scalars (lanes mod 16 alias) ----
    const int  e16 = w * 16 + col;
    const long evA = base + e16;
    int idA = 0, winA = 0; float dtA = 0.f;
    if (full || evA < n) {
        idA  = ids[evA];
        dtA  = ts[evA] - lut[idA];
        winA = (winner[idA] == (int)evA) ? 1 : 0;
    }
    if (l < 16) { sid[e16] = idA; swin[e16] = winA; }

    // ---- phase B load pass: issue all 8 global 16B loads back-to-back ----
    f32x4 xv0, xv1, xv2, xv3, hv0, hv1, hv2, hv3;
    float dt0, dt1, dt2, dt3;
    {
        int   i0 = __shfl(idA, 0 * 4 + rowg), i1 = __shfl(idA, 1 * 4 + rowg);
        int   i2 = __shfl(idA, 2 * 4 + rowg), i3 = __shfl(idA, 3 * 4 + rowg);
        dt0 = __shfl(dtA, 0 * 4 + rowg); dt1 = __shfl(dtA, 1 * 4 + rowg);
        dt2 = __shfl(dtA, 2 * 4 + rowg); dt3 = __shfl(dtA, 3 * 4 + rowg);
        const f32x4* emb4 = (const f32x4*)emb;
        const f32x4* mem4 = (const f32x4*)mem;
        const size_t e0 = (size_t)(base + w * 16 + 0 * 4 + rowg) * 16 + col;
        const size_t e1 = (size_t)(base + w * 16 + 1 * 4 + rowg) * 16 + col;
        const size_t e2 = (size_t)(base + w * 16 + 2 * 4 + rowg) * 16 + col;
        const size_t e3 = (size_t)(base + w * 16 + 3 * 4 + rowg) * 16 + col;
        if (full) {
            xv0 = __builtin_nontemporal_load(&emb4[e0]);
            xv1 = __builtin_nontemporal_load(&emb4[e1]);
            xv2 = __builtin_nontemporal_load(&emb4[e2]);
            xv3 = __builtin_nontemporal_load(&emb4[e3]);
            hv0 = mem4[(size_t)i0 * 16 + col];
            hv1 = mem4[(size_t)i1 * 16 + col];
            hv2 = mem4[(size_t)i2 * 16 + col];
            hv3 = mem4[(size_t)i3 * 16 + col];
        } else {
            f32x4 z = {0.f, 0.f, 0.f, 0.f};
            xv0 = xv1 = xv2 = xv3 = hv0 = hv1 = hv2 = hv3 = z;
            if (base + w * 16 + 0 * 4 + rowg < n) { xv0 = emb4[e0]; hv0 = mem4[(size_t)i0 * 16 + col]; }
            if (base + w * 16 + 1 * 4 + rowg < n) { xv1 = emb4[e1]; hv1 = mem4[(size_t)i1 * 16 + col]; }
            if (base + w * 16 + 2 * 4 + rowg < n) { xv2 = emb4[e2]; hv2 = mem4[(size_t)i2 * 16 + col]; }
            if (base + w * 16 + 3 * 4 + rowg < n) { xv3 = emb4[e3]; hv3 = mem4[(size_t)i3 * 16 + col]; }
        }
    }

    // ---- phase B convert/write pass ----
    const f32x4 wt4 = ((const f32x4*)Wt)[col];
    const f32x4 bt4 = ((const f32x4*)bt)[col];
    {
        #define CONV_WRITE(XV, HV, DT, IT)                                           \
        {                                                                            \
            int r = w * 16 + (IT) * 4 + rowg;                                        \
            f32x4 x = XV;                                                            \
            x.x = fmaf(DT, wt4.x, x.x + bt4.x);                                      \
            x.y = fmaf(DT, wt4.y, x.y + bt4.y);                                      \
            x.z = fmaf(DT, wt4.z, x.z + bt4.z);                                      \
            x.w = fmaf(DT, wt4.w, x.w + bt4.w);                                      \
            f16x4 xh, xl, hh;                                                        \
            _Float16 a;                                                              \
            a = (_Float16)x.x; xh[0] = a; xl[0] = (_Float16)(x.x - (float)a);        \
            a = (_Float16)x.y; xh[1] = a; xl[1] = (_Float16)(x.y - (float)a);        \
            a = (_Float16)x.z; xh[2] = a; xl[2] = (_Float16)(x.z - (float)a);        \
            a = (_Float16)x.w; xh[3] = a; xl[3] = (_Float16)(x.w - (float)a);        \
            hh[0] = (_Float16)(HV).x; hh[1] = (_Float16)(HV).y;                      \
            hh[2] = (_Float16)(HV).z; hh[3] = (_Float16)(HV).w;                      \
            *(f16x4*)&xhh[r][col * 4]      = xh;                                     \
            *(f16x4*)&xhl[r][col * 4]      = xl;                                     \
            *(f16x4*)&xhh[r][64 + col * 4] = hh;                                     \
        }
        CONV_WRITE(xv0, hv0, dt0, 0)
        CONV_WRITE(xv1, hv1, dt1, 1)
        CONV_WRITE(xv2, hv2, dt2, 2)
        CONV_WRITE(xv3, hv3, dt3, 3)
        #undef CONV_WRITE
    }

    // persistent B fragments for this wave's 4 gate tiles (L2-resident)
    const f16x8* H = (const f16x8*)bhi;
    const f16x8* L = (const f16x8*)blo;
    f16x8 BRh0 = H[(size_t)(w * 4 + 0) * 64 + l];
    f16x8 BRh1 = H[(size_t)(w * 4 + 1) * 64 + l];
    f16x8 BRh2 = H[(size_t)(w * 4 + 2) * 64 + l];
    f16x8 BRh3 = H[(size_t)(w * 4 + 3) * 64 + l];
    f16x8 BRl0 = L[(size_t)(w * 4 + 0) * 64 + l];
    f16x8 BRl1 = L[(size_t)(w * 4 + 1) * 64 + l];
    f16x8 BZh0 = H[(size_t)((4 + w) * 4 + 0) * 64 + l];
    f16x8 BZh1 = H[(size_t)((4 + w) * 4 + 1) * 64 + l];
    f16x8 BZh2 = H[(size_t)((4 + w) * 4 + 2) * 64 + l];
    f16x8 BZh3 = H[(size_t)((4 + w) * 4 + 3) * 64 + l];
    f16x8 BZl0 = L[(size_t)((4 + w) * 4 + 0) * 64 + l];
    f16x8 BZl1 = L[(size_t)((4 + w) * 4 + 1) * 64 + l];
    f16x8 BIh0 = H[(size_t)((8 + w) * 4 + 0) * 64 + l];
    f16x8 BIh1 = H[(size_t)((8 + w) * 4 + 1) * 64 + l];
    f16x8 BIl0 = L[(size_t)((8 + w) * 4 + 0) * 64 + l];
    f16x8 BIl1 = L[(size_t)((8 + w) * 4 + 1) * 64 + l];
    f16x8 BHh0 = H[(size_t)((12 + w) * 4 + 2) * 64 + l];
    f16x8 BHh1 = H[(size_t)((12 + w) * 4 + 3) * 64 + l];

    const float bR  = bih[d] + bhh[d];
    const float bZ  = bih[64 + d] + bhh[64 + d];
    const float bIN = bih[128 + d];
    const float bHN = bhh[128 + d];

    __syncthreads();

    // ---- 4 M-tiles of 16 events each ----
    #pragma unroll
    for (int mt = 0; mt < 4; ++mt) {
        const int arow = mt * 16 + col;
        const int k0   = rowg * 8;
        f16x8 Ah0 = *(const f16x8*)&xhh[arow][0 * 32 + k0];
        f16x8 Ah1 = *(const f16x8*)&xhh[arow][1 * 32 + k0];
        f16x8 Ah2 = *(const f16x8*)&xhh[arow][2 * 32 + k0];
        f16x8 Ah3 = *(const f16x8*)&xhh[arow][3 * 32 + k0];
        f16x8 Al0 = *(const f16x8*)&xhl[arow][0 * 32 + k0];
        f16x8 Al1 = *(const f16x8*)&xhl[arow][1 * 32 + k0];

        f32x4 aR = {0,0,0,0}, aZ = {0,0,0,0}, aI = {0,0,0,0}, aH = {0,0,0,0};
        __builtin_amdgcn_s_setprio(1);
        aR = MFMA(aR, Ah0, BRh0); aR = MFMA(aR, Ah0, BRl0); aR = MFMA(aR, Al0, BRh0);
        aR = MFMA(aR, Ah1, BRh1); aR = MFMA(aR, Ah1, BRl1); aR = MFMA(aR, Al1, BRh1);
        aR = MFMA(aR, Ah2, BRh2); aR = MFMA(aR, Ah3, BRh3);
        aZ = MFMA(aZ, Ah0, BZh0); aZ = MFMA(aZ, Ah0, BZl0); aZ = MFMA(aZ, Al0, BZh0);
        aZ = MFMA(aZ, Ah1, BZh1); aZ = MFMA(aZ, Ah1, BZl1); aZ = MFMA(aZ, Al1, BZh1);
        aZ = MFMA(aZ, Ah2, BZh2); aZ = MFMA(aZ, Ah3, BZh3);
        aI = MFMA(aI, Ah0, BIh0); aI = MFMA(aI, Ah0, BIl0); aI = MFMA(aI, Al0, BIh0);
        aI = MFMA(aI, Ah1, BIh1); aI = MFMA(aI, Ah1, BIl1); aI = MFMA(aI, Al1, BIh1);
        aH = MFMA(aH, Ah2, BHh0); aH = MFMA(aH, Ah3, BHh1);
        __builtin_amdgcn_s_setprio(0);

        #pragma unroll
        for (int r = 0; r < 4; ++r) {
            int  eloc = mt * 16 + rowg * 4 + r;
            long ev   = base + eloc;
            if (full || ev < n) {
                float rr = sigmoidf_(aR[r] + bR);
                float zz = sigmoidf_(aZ[r] + bZ);
                float nn = tanh_fast(aI[r] + bIN + rr * (aH[r] + bHN));
                float hv = (float)xhh[eloc][64 + d];
                float o  = (1.f - zz) * nn + zz * hv;
                __builtin_nontemporal_store(o, &out0[(size_t)ev * 64 + d]);
                if (swin[eloc])
                    __builtin_nontemporal_store(o, &out1[(size_t)sid[eloc] * 64 + d]);
            }
        }
    }
}

extern "C" void kernel_launch(void* const* d_in, const int* in_sizes, int n_in,
                              void* d_out, int out_size, void* d_ws, size_t ws_size,
                              hipStream_t stream) {
    const int*   ids = (const int*)  d_in[0];
    const float* emb = (const float*)d_in[1];
    const float* ts  = (const float*)d_in[2];
    const float* mem = (const float*)d_in[3];
    const float* lut = (const float*)d_in[4];
    const float* Wt  = (const float*)d_in[5];
    const float* bt  = (const float*)d_in[6];
    const float* Wih = (const float*)d_in[7];
    const float* Whh = (const float*)d_in[8];
    const float* bih = (const float*)d_in[9];
    const float* bhh = (const float*)d_in[10];

    const int N         = in_sizes[0];
    const int NUM_NODES = in_sizes[4];

    float* out0 = (float*)d_out;                    // [N,64]
    float* out1 = out0 + (size_t)N * DD;            // [NUM_NODES,64]
    float* out2 = out1 + (size_t)NUM_NODES * DD;    // [NUM_NODES]

    _Float16* bfragH = (_Float16*)d_ws;                      // 64 KB
    _Float16* bfragL = bfragH + 64 * 64 * 8;                 // 64 KB
    int*      winner = (int*)((char*)d_ws + 128 * 1024);     // NUM_NODES * 4 B

    int initBlocks = (NUM_NODES + 255) / 256;
    k_prep_init<<<16 + initBlocks, 256, 0, stream>>>(Wih, Whh, bfragH, bfragL,
                                                     winner, NUM_NODES);
    k_vote<<<(N + 255) / 256, 256, 0, stream>>>(ids, winner, N);

    // Heterogeneous grid: gruBlocks at idx%3==0, tail blocks (64 nodes each) else.
    int gruBlocks  = (N + 63) / 64;                 // 8192 at N=524288
    int totalBlocks = gruBlocks * 3;                // tail capacity 2*gruBlocks >= 15625
    k_main<<<totalBlocks, 256, 0, stream>>>(ids, emb, ts, mem, lut, Wt, bt, bih, bhh,
                                            bfragH, bfragL, winner, out0, out1, out2,
                                            N, NUM_NODES);
}

// Round 11
// 233.227 us; speedup vs baseline: 1.8159x; 1.2435x over previous
//
#include <hip/hip_runtime.h>
#include <cstdint>
#include <cstddef>

#define DD 64

typedef float    f32x4  __attribute__((ext_vector_type(4)));
typedef _Float16 f16x8  __attribute__((ext_vector_type(8)));
typedef _Float16 f16x4  __attribute__((ext_vector_type(4)));

__device__ __forceinline__ float sigmoidf_(float x) {
    return 1.0f / (1.0f + __expf(-x));
}
__device__ __forceinline__ float tanh_fast(float x) {
    float ax = fabsf(x);
    float t = 1.0f - 2.0f / (1.0f + __expf(2.0f * ax));
    return copysignf(t, x);
}
__device__ __forceinline__ f32x4 MFMA(f32x4 c, f16x8 a, f16x8 b) {
    return __builtin_amdgcn_mfma_f32_16x16x32_f16(a, b, c, 0, 0, 0);
}

// ---------------- winner voting (winner[] lives in out2 region) ----------------
__global__ void k_init(int* __restrict__ winner, int num_nodes) {
    int i = blockIdx.x * blockDim.x + threadIdx.x;
    if (i < num_nodes) winner[i] = -1;
}
__global__ void k_vote(const int* __restrict__ ids, int* __restrict__ winner, int n) {
    int i = blockIdx.x * blockDim.x + threadIdx.x;
    if (i < n) atomicMax(&winner[ids[i]], i);
}

// ---------------- build B fragments (hi/lo split fp16) into ws ----------------
// Conceptual B[128][256]: cols 0..63 r-gate (K: x then h), 64..127 z-gate,
// 128..191 i_n (x only), 192..255 h_n (h only).
// Fragment f = g*4+s (g=tile 0..15, s=K-step 0..3); lane l holds
// B[s*32+(l>>4)*8+j][g*16+(l&15)], j=0..7, packed 8 fp16 = 16B.
__global__ void k_prep(const float* __restrict__ Wih, const float* __restrict__ Whh,
                       _Float16* __restrict__ bhi, _Float16* __restrict__ blo)
{
    int f = blockIdx.x;        // 0..63
    int l = threadIdx.x;       // 0..63
    int g = f >> 2, s = f & 3;
    int c = g * 16 + (l & 15);
    int grp = c >> 6, d = c & 63;
    int kbase = s * 32 + (l >> 4) * 8;
    int row = (grp == 0) ? d : (grp == 1) ? 64 + d : 128 + d;

    f16x8 hv, lv;
    for (int j = 0; j < 8; ++j) {
        int k = kbase + j;
        float v;
        if (grp <= 1)      v = (k < 64) ? Wih[row * 64 + k] : Whh[row * 64 + (k - 64)];
        else if (grp == 2) v = (k < 64) ? Wih[row * 64 + k] : 0.0f;
        else               v = (k < 64) ? 0.0f : Whh[row * 64 + (k - 64)];
        _Float16 h = (_Float16)v;
        hv[j] = h;
        lv[j] = (_Float16)(v - (float)h);
    }
    size_t off = ((size_t)f * 64 + l);
    ((f16x8*)bhi)[off] = hv;
    ((f16x8*)blo)[off] = lv;
}

// ---------------- main GRU kernel (MFMA, asymmetric split-fp16) ----------------
// One 64-event chunk per block; x split hi/lo, h plain fp16.
// Phase A branch-free; Phase B = T14 split (issue loads, then convert+LDS).
// Epilogue uses PLAIN stores so L2 merges the 4 waves' 64B quarters into full
// 256B lines before writeback (nt bypassed merge -> random 64B HBM granules).
__global__ __launch_bounds__(256, 3) void k_gru(
    const int* __restrict__ ids,
    const float* __restrict__ emb,
    const float* __restrict__ ts,
    const float* __restrict__ mem,
    const float* __restrict__ lut,
    const float* __restrict__ Wt,
    const float* __restrict__ bt,
    const float* __restrict__ bih,
    const float* __restrict__ bhh,
    const _Float16* __restrict__ bhi,
    const _Float16* __restrict__ blo,
    const int* __restrict__ winner,
    float* __restrict__ out0,
    float* __restrict__ out1,
    int n)
{
    __shared__ _Float16 xhh[64][136];   // hi plane: [event][k], k<64 x_hi, k>=64 h
    __shared__ _Float16 xhl[64][72];    // lo plane: x_lo only (k<64)
    __shared__ int sid[64];
    __shared__ int swin[64];

    const int w    = threadIdx.x >> 6;
    const int l    = threadIdx.x & 63;
    const int col  = l & 15;
    const int rowg = l >> 4;
    const int d    = w * 16 + col;      // output dim this lane owns in epilogue

    const long base = (long)blockIdx.x * 64;
    const bool full = (base + 64 <= (long)n);

    // ---- phase A: every lane loads its event's scalars (lanes mod 16 alias) ----
    const int  e16 = w * 16 + col;
    const long evA = base + e16;
    int idA = 0, winA = 0; float dtA = 0.f;
    if (full || evA < n) {
        idA  = ids[evA];
        dtA  = ts[evA] - lut[idA];
        winA = (winner[idA] == (int)evA) ? 1 : 0;
    }
    if (l < 16) { sid[e16] = idA; swin[e16] = winA; }

    // ---- phase B load pass: issue all 8 global 16B loads back-to-back ----
    f32x4 xv0, xv1, xv2, xv3, hv0, hv1, hv2, hv3;
    float dt0, dt1, dt2, dt3;
    {
        int   i0 = __shfl(idA, 0 * 4 + rowg), i1 = __shfl(idA, 1 * 4 + rowg);
        int   i2 = __shfl(idA, 2 * 4 + rowg), i3 = __shfl(idA, 3 * 4 + rowg);
        dt0 = __shfl(dtA, 0 * 4 + rowg); dt1 = __shfl(dtA, 1 * 4 + rowg);
        dt2 = __shfl(dtA, 2 * 4 + rowg); dt3 = __shfl(dtA, 3 * 4 + rowg);
        const f32x4* emb4 = (const f32x4*)emb;
        const f32x4* mem4 = (const f32x4*)mem;
        const size_t e0 = (size_t)(base + w * 16 + 0 * 4 + rowg) * 16 + col;
        const size_t e1 = (size_t)(base + w * 16 + 1 * 4 + rowg) * 16 + col;
        const size_t e2 = (size_t)(base + w * 16 + 2 * 4 + rowg) * 16 + col;
        const size_t e3 = (size_t)(base + w * 16 + 3 * 4 + rowg) * 16 + col;
        if (full) {
            xv0 = __builtin_nontemporal_load(&emb4[e0]);
            xv1 = __builtin_nontemporal_load(&emb4[e1]);
            xv2 = __builtin_nontemporal_load(&emb4[e2]);
            xv3 = __builtin_nontemporal_load(&emb4[e3]);
            hv0 = mem4[(size_t)i0 * 16 + col];
            hv1 = mem4[(size_t)i1 * 16 + col];
            hv2 = mem4[(size_t)i2 * 16 + col];
            hv3 = mem4[(size_t)i3 * 16 + col];
        } else {
            f32x4 z = {0.f, 0.f, 0.f, 0.f};
            xv0 = xv1 = xv2 = xv3 = hv0 = hv1 = hv2 = hv3 = z;
            if (base + w * 16 + 0 * 4 + rowg < n) { xv0 = emb4[e0]; hv0 = mem4[(size_t)i0 * 16 + col]; }
            if (base + w * 16 + 1 * 4 + rowg < n) { xv1 = emb4[e1]; hv1 = mem4[(size_t)i1 * 16 + col]; }
            if (base + w * 16 + 2 * 4 + rowg < n) { xv2 = emb4[e2]; hv2 = mem4[(size_t)i2 * 16 + col]; }
            if (base + w * 16 + 3 * 4 + rowg < n) { xv3 = emb4[e3]; hv3 = mem4[(size_t)i3 * 16 + col]; }
        }
    }

    // ---- phase B convert/write pass ----
    const f32x4 wt4 = ((const f32x4*)Wt)[col];
    const f32x4 bt4 = ((const f32x4*)bt)[col];
    {
        #define CONV_WRITE(XV, HV, DT, IT)                                           \
        {                                                                            \
            int r = w * 16 + (IT) * 4 + rowg;                                        \
            f32x4 x = XV;                                                            \
            x.x = fmaf(DT, wt4.x, x.x + bt4.x);                                      \
            x.y = fmaf(DT, wt4.y, x.y + bt4.y);                                      \
            x.z = fmaf(DT, wt4.z, x.z + bt4.z);                                      \
            x.w = fmaf(DT, wt4.w, x.w + bt4.w);                                      \
            f16x4 xh, xl, hh;                                                        \
            _Float16 a;                                                              \
            a = (_Float16)x.x; xh[0] = a; xl[0] = (_Float16)(x.x - (float)a);        \
            a = (_Float16)x.y; xh[1] = a; xl[1] = (_Float16)(x.y - (float)a);        \
            a = (_Float16)x.z; xh[2] = a; xl[2] = (_Float16)(x.z - (float)a);        \
            a = (_Float16)x.w; xh[3] = a; xl[3] = (_Float16)(x.w - (float)a);        \
            hh[0] = (_Float16)(HV).x; hh[1] = (_Float16)(HV).y;                      \
            hh[2] = (_Float16)(HV).z; hh[3] = (_Float16)(HV).w;                      \
            *(f16x4*)&xhh[r][col * 4]      = xh;                                     \
            *(f16x4*)&xhl[r][col * 4]      = xl;                                     \
            *(f16x4*)&xhh[r][64 + col * 4] = hh;                                     \
        }
        CONV_WRITE(xv0, hv0, dt0, 0)
        CONV_WRITE(xv1, hv1, dt1, 1)
        CONV_WRITE(xv2, hv2, dt2, 2)
        CONV_WRITE(xv3, hv3, dt3, 3)
        #undef CONV_WRITE
    }

    // persistent B fragments for this wave's 4 gate tiles (L2-resident)
    const f16x8* H = (const f16x8*)bhi;
    const f16x8* L = (const f16x8*)blo;
    f16x8 BRh0 = H[(size_t)(w * 4 + 0) * 64 + l];
    f16x8 BRh1 = H[(size_t)(w * 4 + 1) * 64 + l];
    f16x8 BRh2 = H[(size_t)(w * 4 + 2) * 64 + l];
    f16x8 BRh3 = H[(size_t)(w * 4 + 3) * 64 + l];
    f16x8 BRl0 = L[(size_t)(w * 4 + 0) * 64 + l];
    f16x8 BRl1 = L[(size_t)(w * 4 + 1) * 64 + l];
    f16x8 BZh0 = H[(size_t)((4 + w) * 4 + 0) * 64 + l];
    f16x8 BZh1 = H[(size_t)((4 + w) * 4 + 1) * 64 + l];
    f16x8 BZh2 = H[(size_t)((4 + w) * 4 + 2) * 64 + l];
    f16x8 BZh3 = H[(size_t)((4 + w) * 4 + 3) * 64 + l];
    f16x8 BZl0 = L[(size_t)((4 + w) * 4 + 0) * 64 + l];
    f16x8 BZl1 = L[(size_t)((4 + w) * 4 + 1) * 64 + l];
    f16x8 BIh0 = H[(size_t)((8 + w) * 4 + 0) * 64 + l];
    f16x8 BIh1 = H[(size_t)((8 + w) * 4 + 1) * 64 + l];
    f16x8 BIl0 = L[(size_t)((8 + w) * 4 + 0) * 64 + l];
    f16x8 BIl1 = L[(size_t)((8 + w) * 4 + 1) * 64 + l];
    f16x8 BHh0 = H[(size_t)((12 + w) * 4 + 2) * 64 + l];
    f16x8 BHh1 = H[(size_t)((12 + w) * 4 + 3) * 64 + l];

    const float bR  = bih[d] + bhh[d];
    const float bZ  = bih[64 + d] + bhh[64 + d];
    const float bIN = bih[128 + d];
    const float bHN = bhh[128 + d];

    __syncthreads();

    // ---- 4 M-tiles of 16 events each ----
    #pragma unroll
    for (int mt = 0; mt < 4; ++mt) {
        const int arow = mt * 16 + col;
        const int k0   = rowg * 8;
        f16x8 Ah0 = *(const f16x8*)&xhh[arow][0 * 32 + k0];
        f16x8 Ah1 = *(const f16x8*)&xhh[arow][1 * 32 + k0];
        f16x8 Ah2 = *(const f16x8*)&xhh[arow][2 * 32 + k0];
        f16x8 Ah3 = *(const f16x8*)&xhh[arow][3 * 32 + k0];
        f16x8 Al0 = *(const f16x8*)&xhl[arow][0 * 32 + k0];
        f16x8 Al1 = *(const f16x8*)&xhl[arow][1 * 32 + k0];

        f32x4 aR = {0,0,0,0}, aZ = {0,0,0,0}, aI = {0,0,0,0}, aH = {0,0,0,0};
        __builtin_amdgcn_s_setprio(1);
        aR = MFMA(aR, Ah0, BRh0); aR = MFMA(aR, Ah0, BRl0); aR = MFMA(aR, Al0, BRh0);
        aR = MFMA(aR, Ah1, BRh1); aR = MFMA(aR, Ah1, BRl1); aR = MFMA(aR, Al1, BRh1);
        aR = MFMA(aR, Ah2, BRh2); aR = MFMA(aR, Ah3, BRh3);
        aZ = MFMA(aZ, Ah0, BZh0); aZ = MFMA(aZ, Ah0, BZl0); aZ = MFMA(aZ, Al0, BZh0);
        aZ = MFMA(aZ, Ah1, BZh1); aZ = MFMA(aZ, Ah1, BZl1); aZ = MFMA(aZ, Al1, BZh1);
        aZ = MFMA(aZ, Ah2, BZh2); aZ = MFMA(aZ, Ah3, BZh3);
        aI = MFMA(aI, Ah0, BIh0); aI = MFMA(aI, Ah0, BIl0); aI = MFMA(aI, Al0, BIh0);
        aI = MFMA(aI, Ah1, BIh1); aI = MFMA(aI, Ah1, BIl1); aI = MFMA(aI, Al1, BIh1);
        aH = MFMA(aH, Ah2, BHh0); aH = MFMA(aH, Ah3, BHh1);
        __builtin_amdgcn_s_setprio(0);

        #pragma unroll
        for (int r = 0; r < 4; ++r) {
            int  eloc = mt * 16 + rowg * 4 + r;
            long ev   = base + eloc;
            if (full || ev < n) {
                float rr = sigmoidf_(aR[r] + bR);
                float zz = sigmoidf_(aZ[r] + bZ);
                float nn = tanh_fast(aI[r] + bIN + rr * (aH[r] + bHN));
                float hv = (float)xhh[eloc][64 + d];
                float o  = (1.f - zz) * nn + zz * hv;
                out0[(size_t)ev * 64 + d] = o;                       // plain: L2 merges
                if (swin[eloc])
                    out1[(size_t)sid[eloc] * 64 + d] = o;            // plain: L2 merges
            }
        }
    }
}

// ---------------- fused tail: loser-row copy + timestamp scatter ----------------
// winner stored IN out2; each 16-thread group reads its node's winner, then lane
// c==0 overwrites that same slot (read-before-write within the wave -> safe).
__global__ void k_tail(float* out2,
                       const f32x4* __restrict__ mem4,
                       f32x4* __restrict__ out14,
                       const float* __restrict__ ts,
                       const float* __restrict__ lut,
                       int num_nodes)
{
    int idx = blockIdx.x * blockDim.x + threadIdx.x;
    if (idx >= num_nodes * 16) return;
    int nidx = idx >> 4;
    int c    = idx & 15;
    int wv = reinterpret_cast<const int*>(out2)[nidx];
    if (wv < 0) {
        f32x4 v = __builtin_nontemporal_load(&mem4[idx]);
        __builtin_nontemporal_store(v, &out14[idx]);
    }
    if (c == 0) out2[nidx] = (wv >= 0) ? ts[wv] : lut[nidx];
}

extern "C" void kernel_launch(void* const* d_in, const int* in_sizes, int n_in,
                              void* d_out, int out_size, void* d_ws, size_t ws_size,
                              hipStream_t stream) {
    const int*   ids = (const int*)  d_in[0];
    const float* emb = (const float*)d_in[1];
    const float* ts  = (const float*)d_in[2];
    const float* mem = (const float*)d_in[3];
    const float* lut = (const float*)d_in[4];
    const float* Wt  = (const float*)d_in[5];
    const float* bt  = (const float*)d_in[6];
    const float* Wih = (const float*)d_in[7];
    const float* Whh = (const float*)d_in[8];
    const float* bih = (const float*)d_in[9];
    const float* bhh = (const float*)d_in[10];

    const int N         = in_sizes[0];
    const int NUM_NODES = in_sizes[4];

    float* out0 = (float*)d_out;                    // [N,64]
    float* out1 = out0 + (size_t)N * DD;            // [NUM_NODES,64]
    float* out2 = out1 + (size_t)NUM_NODES * DD;    // [NUM_NODES]
    int*   winner = (int*)out2;

    _Float16* bfragH = (_Float16*)d_ws;             // 64 KB
    _Float16* bfragL = bfragH + 64 * 64 * 8;        // 64 KB

    k_prep<<<64, 64, 0, stream>>>(Wih, Whh, bfragH, bfragL);
    k_init<<<(NUM_NODES + 255) / 256, 256, 0, stream>>>(winner, NUM_NODES);
    k_vote<<<(N + 255) / 256, 256, 0, stream>>>(ids, winner, N);

    int nchunks = (N + 63) / 64;
    k_gru<<<nchunks, 256, 0, stream>>>(ids, emb, ts, mem, lut, Wt, bt, bih, bhh,
                                       bfragH, bfragL, winner, out0, out1, N);

    long vec = (long)NUM_NODES * 16;
    k_tail<<<(int)((vec + 255) / 256), 256, 0, stream>>>(
        out2, (const f32x4*)mem, (f32x4*)out1, ts, lut, NUM_NODES);
}

// Round 12
// 229.847 us; speedup vs baseline: 1.8426x; 1.0147x over previous
//
#include <hip/hip_runtime.h>
#include <cstdint>
#include <cstddef>

#define DD 64

typedef float    f32x4  __attribute__((ext_vector_type(4)));
typedef _Float16 f16x8  __attribute__((ext_vector_type(8)));
typedef _Float16 f16x4  __attribute__((ext_vector_type(4)));

__device__ __forceinline__ float sigmoidf_(float x) {
    return 1.0f / (1.0f + __expf(-x));
}
__device__ __forceinline__ float tanh_fast(float x) {
    float ax = fabsf(x);
    float t = 1.0f - 2.0f / (1.0f + __expf(2.0f * ax));
    return copysignf(t, x);
}
__device__ __forceinline__ f32x4 MFMA(f32x4 c, f16x8 a, f16x8 b) {
    return __builtin_amdgcn_mfma_f32_16x16x32_f16(a, b, c, 0, 0, 0);
}

// ---------------- fused: B-fragment build (blocks 0..15) + winner init ----------------
// B[128][256]: cols 0..63 r (K: x|h), 64..127 z, 128..191 i_n (x), 192..255 h_n (h).
// Fragment f = g*4+s; lane l holds B[s*32+(l>>4)*8+j][g*16+(l&15)], j=0..7.
__global__ void k_prep_init(const float* __restrict__ Wih, const float* __restrict__ Whh,
                            _Float16* __restrict__ bhi, _Float16* __restrict__ blo,
                            int* __restrict__ winner, int num_nodes)
{
    if (blockIdx.x < 16) {
        int f = blockIdx.x * 4 + (threadIdx.x >> 6);   // 0..63
        int l = threadIdx.x & 63;
        int g = f >> 2, s = f & 3;
        int c = g * 16 + (l & 15);
        int grp = c >> 6, dd = c & 63;
        int kbase = s * 32 + (l >> 4) * 8;
        int row = (grp == 0) ? dd : (grp == 1) ? 64 + dd : 128 + dd;

        f16x8 hv, lv;
        for (int j = 0; j < 8; ++j) {
            int k = kbase + j;
            float v;
            if (grp <= 1)      v = (k < 64) ? Wih[row * 64 + k] : Whh[row * 64 + (k - 64)];
            else if (grp == 2) v = (k < 64) ? Wih[row * 64 + k] : 0.0f;
            else               v = (k < 64) ? 0.0f : Whh[row * 64 + (k - 64)];
            _Float16 h = (_Float16)v;
            hv[j] = h;
            lv[j] = (_Float16)(v - (float)h);
        }
        size_t off = ((size_t)f * 64 + l);
        ((f16x8*)bhi)[off] = hv;
        ((f16x8*)blo)[off] = lv;
    } else {
        int i = (int)(blockIdx.x - 16) * 256 + threadIdx.x;
        if (i < num_nodes) winner[i] = -1;
    }
}

__global__ void k_vote(const int* __restrict__ ids, int* __restrict__ winner, int n) {
    int i = blockIdx.x * blockDim.x + threadIdx.x;
    if (i < n) atomicMax(&winner[ids[i]], i);
}

// ---------------- main GRU kernel (MFMA, asymmetric split-fp16) ----------------
// r7/r11 structure, single variable changed: __launch_bounds__(256,4) -> 4 blocks/CU
// (VGPR 84 < 128 cap, LDS 27.1KB*4 = 108KB < 160KB; no spill expected).
__global__ __launch_bounds__(256, 4) void k_gru(
    const int* __restrict__ ids,
    const float* __restrict__ emb,
    const float* __restrict__ ts,
    const float* __restrict__ mem,
    const float* __restrict__ lut,
    const float* __restrict__ Wt,
    const float* __restrict__ bt,
    const float* __restrict__ bih,
    const float* __restrict__ bhh,
    const _Float16* __restrict__ bhi,
    const _Float16* __restrict__ blo,
    const int* __restrict__ winner,
    float* __restrict__ out0,
    float* __restrict__ out1,
    int n)
{
    __shared__ _Float16 xhh[64][136];   // hi plane: [event][k], k<64 x_hi, k>=64 h
    __shared__ _Float16 xhl[64][72];    // lo plane: x_lo only (k<64)
    __shared__ int sid[64];
    __shared__ int swin[64];

    const int w    = threadIdx.x >> 6;
    const int l    = threadIdx.x & 63;
    const int col  = l & 15;
    const int rowg = l >> 4;
    const int d    = w * 16 + col;      // output dim this lane owns in epilogue

    const long base = (long)blockIdx.x * 64;
    const bool full = (base + 64 <= (long)n);

    // ---- phase A: every lane loads its event's scalars (lanes mod 16 alias) ----
    const int  e16 = w * 16 + col;
    const long evA = base + e16;
    int idA = 0, winA = 0; float dtA = 0.f;
    if (full || evA < n) {
        idA  = ids[evA];
        dtA  = ts[evA] - lut[idA];
        winA = (winner[idA] == (int)evA) ? 1 : 0;
    }
    if (l < 16) { sid[e16] = idA; swin[e16] = winA; }

    // ---- phase B load pass: issue all 8 global 16B loads back-to-back ----
    f32x4 xv0, xv1, xv2, xv3, hv0, hv1, hv2, hv3;
    float dt0, dt1, dt2, dt3;
    {
        int   i0 = __shfl(idA, 0 * 4 + rowg), i1 = __shfl(idA, 1 * 4 + rowg);
        int   i2 = __shfl(idA, 2 * 4 + rowg), i3 = __shfl(idA, 3 * 4 + rowg);
        dt0 = __shfl(dtA, 0 * 4 + rowg); dt1 = __shfl(dtA, 1 * 4 + rowg);
        dt2 = __shfl(dtA, 2 * 4 + rowg); dt3 = __shfl(dtA, 3 * 4 + rowg);
        const f32x4* emb4 = (const f32x4*)emb;
        const f32x4* mem4 = (const f32x4*)mem;
        const size_t e0 = (size_t)(base + w * 16 + 0 * 4 + rowg) * 16 + col;
        const size_t e1 = (size_t)(base + w * 16 + 1 * 4 + rowg) * 16 + col;
        const size_t e2 = (size_t)(base + w * 16 + 2 * 4 + rowg) * 16 + col;
        const size_t e3 = (size_t)(base + w * 16 + 3 * 4 + rowg) * 16 + col;
        if (full) {
            xv0 = __builtin_nontemporal_load(&emb4[e0]);
            xv1 = __builtin_nontemporal_load(&emb4[e1]);
            xv2 = __builtin_nontemporal_load(&emb4[e2]);
            xv3 = __builtin_nontemporal_load(&emb4[e3]);
            hv0 = mem4[(size_t)i0 * 16 + col];
            hv1 = mem4[(size_t)i1 * 16 + col];
            hv2 = mem4[(size_t)i2 * 16 + col];
            hv3 = mem4[(size_t)i3 * 16 + col];
        } else {
            f32x4 z = {0.f, 0.f, 0.f, 0.f};
            xv0 = xv1 = xv2 = xv3 = hv0 = hv1 = hv2 = hv3 = z;
            if (base + w * 16 + 0 * 4 + rowg < n) { xv0 = emb4[e0]; hv0 = mem4[(size_t)i0 * 16 + col]; }
            if (base + w * 16 + 1 * 4 + rowg < n) { xv1 = emb4[e1]; hv1 = mem4[(size_t)i1 * 16 + col]; }
            if (base + w * 16 + 2 * 4 + rowg < n) { xv2 = emb4[e2]; hv2 = mem4[(size_t)i2 * 16 + col]; }
            if (base + w * 16 + 3 * 4 + rowg < n) { xv3 = emb4[e3]; hv3 = mem4[(size_t)i3 * 16 + col]; }
        }
    }

    // ---- phase B convert/write pass ----
    const f32x4 wt4 = ((const f32x4*)Wt)[col];
    const f32x4 bt4 = ((const f32x4*)bt)[col];
    {
        #define CONV_WRITE(XV, HV, DT, IT)                                           \
        {                                                                            \
            int r = w * 16 + (IT) * 4 + rowg;                                        \
            f32x4 x = XV;                                                            \
            x.x = fmaf(DT, wt4.x, x.x + bt4.x);                                      \
            x.y = fmaf(DT, wt4.y, x.y + bt4.y);                                      \
            x.z = fmaf(DT, wt4.z, x.z + bt4.z);                                      \
            x.w = fmaf(DT, wt4.w, x.w + bt4.w);                                      \
            f16x4 xh, xl, hh;                                                        \
            _Float16 a;                                                              \
            a = (_Float16)x.x; xh[0] = a; xl[0] = (_Float16)(x.x - (float)a);        \
            a = (_Float16)x.y; xh[1] = a; xl[1] = (_Float16)(x.y - (float)a);        \
            a = (_Float16)x.z; xh[2] = a; xl[2] = (_Float16)(x.z - (float)a);        \
            a = (_Float16)x.w; xh[3] = a; xl[3] = (_Float16)(x.w - (float)a);        \
            hh[0] = (_Float16)(HV).x; hh[1] = (_Float16)(HV).y;                      \
            hh[2] = (_Float16)(HV).z; hh[3] = (_Float16)(HV).w;                      \
            *(f16x4*)&xhh[r][col * 4]      = xh;                                     \
            *(f16x4*)&xhl[r][col * 4]      = xl;                                     \
            *(f16x4*)&xhh[r][64 + col * 4] = hh;                                     \
        }
        CONV_WRITE(xv0, hv0, dt0, 0)
        CONV_WRITE(xv1, hv1, dt1, 1)
        CONV_WRITE(xv2, hv2, dt2, 2)
        CONV_WRITE(xv3, hv3, dt3, 3)
        #undef CONV_WRITE
    }

    // persistent B fragments for this wave's 4 gate tiles (L2-resident)
    const f16x8* H = (const f16x8*)bhi;
    const f16x8* L = (const f16x8*)blo;
    f16x8 BRh0 = H[(size_t)(w * 4 + 0) * 64 + l];
    f16x8 BRh1 = H[(size_t)(w * 4 + 1) * 64 + l];
    f16x8 BRh2 = H[(size_t)(w * 4 + 2) * 64 + l];
    f16x8 BRh3 = H[(size_t)(w * 4 + 3) * 64 + l];
    f16x8 BRl0 = L[(size_t)(w * 4 + 0) * 64 + l];
    f16x8 BRl1 = L[(size_t)(w * 4 + 1) * 64 + l];
    f16x8 BZh0 = H[(size_t)((4 + w) * 4 + 0) * 64 + l];
    f16x8 BZh1 = H[(size_t)((4 + w) * 4 + 1) * 64 + l];
    f16x8 BZh2 = H[(size_t)((4 + w) * 4 + 2) * 64 + l];
    f16x8 BZh3 = H[(size_t)((4 + w) * 4 + 3) * 64 + l];
    f16x8 BZl0 = L[(size_t)((4 + w) * 4 + 0) * 64 + l];
    f16x8 BZl1 = L[(size_t)((4 + w) * 4 + 1) * 64 + l];
    f16x8 BIh0 = H[(size_t)((8 + w) * 4 + 0) * 64 + l];
    f16x8 BIh1 = H[(size_t)((8 + w) * 4 + 1) * 64 + l];
    f16x8 BIl0 = L[(size_t)((8 + w) * 4 + 0) * 64 + l];
    f16x8 BIl1 = L[(size_t)((8 + w) * 4 + 1) * 64 + l];
    f16x8 BHh0 = H[(size_t)((12 + w) * 4 + 2) * 64 + l];
    f16x8 BHh1 = H[(size_t)((12 + w) * 4 + 3) * 64 + l];

    const float bR  = bih[d] + bhh[d];
    const float bZ  = bih[64 + d] + bhh[64 + d];
    const float bIN = bih[128 + d];
    const float bHN = bhh[128 + d];

    __syncthreads();

    // ---- 4 M-tiles of 16 events each ----
    #pragma unroll
    for (int mt = 0; mt < 4; ++mt) {
        const int arow = mt * 16 + col;
        const int k0   = rowg * 8;
        f16x8 Ah0 = *(const f16x8*)&xhh[arow][0 * 32 + k0];
        f16x8 Ah1 = *(const f16x8*)&xhh[arow][1 * 32 + k0];
        f16x8 Ah2 = *(const f16x8*)&xhh[arow][2 * 32 + k0];
        f16x8 Ah3 = *(const f16x8*)&xhh[arow][3 * 32 + k0];
        f16x8 Al0 = *(const f16x8*)&xhl[arow][0 * 32 + k0];
        f16x8 Al1 = *(const f16x8*)&xhl[arow][1 * 32 + k0];

        f32x4 aR = {0,0,0,0}, aZ = {0,0,0,0}, aI = {0,0,0,0}, aH = {0,0,0,0};
        __builtin_amdgcn_s_setprio(1);
        aR = MFMA(aR, Ah0, BRh0); aR = MFMA(aR, Ah0, BRl0); aR = MFMA(aR, Al0, BRh0);
        aR = MFMA(aR, Ah1, BRh1); aR = MFMA(aR, Ah1, BRl1); aR = MFMA(aR, Al1, BRh1);
        aR = MFMA(aR, Ah2, BRh2); aR = MFMA(aR, Ah3, BRh3);
        aZ = MFMA(aZ, Ah0, BZh0); aZ = MFMA(aZ, Ah0, BZl0); aZ = MFMA(aZ, Al0, BZh0);
        aZ = MFMA(aZ, Ah1, BZh1); aZ = MFMA(aZ, Ah1, BZl1); aZ = MFMA(aZ, Al1, BZh1);
        aZ = MFMA(aZ, Ah2, BZh2); aZ = MFMA(aZ, Ah3, BZh3);
        aI = MFMA(aI, Ah0, BIh0); aI = MFMA(aI, Ah0, BIl0); aI = MFMA(aI, Al0, BIh0);
        aI = MFMA(aI, Ah1, BIh1); aI = MFMA(aI, Ah1, BIl1); aI = MFMA(aI, Al1, BIh1);
        aH = MFMA(aH, Ah2, BHh0); aH = MFMA(aH, Ah3, BHh1);
        __builtin_amdgcn_s_setprio(0);

        #pragma unroll
        for (int r = 0; r < 4; ++r) {
            int  eloc = mt * 16 + rowg * 4 + r;
            long ev   = base + eloc;
            if (full || ev < n) {
                float rr = sigmoidf_(aR[r] + bR);
                float zz = sigmoidf_(aZ[r] + bZ);
                float nn = tanh_fast(aI[r] + bIN + rr * (aH[r] + bHN));
                float hv = (float)xhh[eloc][64 + d];
                float o  = (1.f - zz) * nn + zz * hv;
                out0[(size_t)ev * 64 + d] = o;
                if (swin[eloc])
                    out1[(size_t)sid[eloc] * 64 + d] = o;
            }
        }
    }
}

// ---------------- fused tail: loser-row copy + timestamp scatter ----------------
// winner stored IN out2; each 16-thread group reads its node's winner, then lane
// c==0 overwrites that same slot (read-before-write within the wave -> safe).
__global__ void k_tail(float* out2,
                       const f32x4* __restrict__ mem4,
                       f32x4* __restrict__ out14,
                       const float* __restrict__ ts,
                       const float* __restrict__ lut,
                       int num_nodes)
{
    int idx = blockIdx.x * blockDim.x + threadIdx.x;
    if (idx >= num_nodes * 16) return;
    int nidx = idx >> 4;
    int c    = idx & 15;
    int wv = reinterpret_cast<const int*>(out2)[nidx];
    if (wv < 0) {
        f32x4 v = __builtin_nontemporal_load(&mem4[idx]);
        __builtin_nontemporal_store(v, &out14[idx]);
    }
    if (c == 0) out2[nidx] = (wv >= 0) ? ts[wv] : lut[nidx];
}

extern "C" void kernel_launch(void* const* d_in, const int* in_sizes, int n_in,
                              void* d_out, int out_size, void* d_ws, size_t ws_size,
                              hipStream_t stream) {
    const int*   ids = (const int*)  d_in[0];
    const float* emb = (const float*)d_in[1];
    const float* ts  = (const float*)d_in[2];
    const float* mem = (const float*)d_in[3];
    const float* lut = (const float*)d_in[4];
    const float* Wt  = (const float*)d_in[5];
    const float* bt  = (const float*)d_in[6];
    const float* Wih = (const float*)d_in[7];
    const float* Whh = (const float*)d_in[8];
    const float* bih = (const float*)d_in[9];
    const float* bhh = (const float*)d_in[10];

    const int N         = in_sizes[0];
    const int NUM_NODES = in_sizes[4];

    float* out0 = (float*)d_out;                    // [N,64]
    float* out1 = out0 + (size_t)N * DD;            // [NUM_NODES,64]
    float* out2 = out1 + (size_t)NUM_NODES * DD;    // [NUM_NODES]
    int*   winner = (int*)out2;

    _Float16* bfragH = (_Float16*)d_ws;             // 64 KB
    _Float16* bfragL = bfragH + 64 * 64 * 8;        // 64 KB

    int initBlocks = (NUM_NODES + 255) / 256;
    k_prep_init<<<16 + initBlocks, 256, 0, stream>>>(Wih, Whh, bfragH, bfragL,
                                                     winner, NUM_NODES);
    k_vote<<<(N + 255) / 256, 256, 0, stream>>>(ids, winner, N);

    int nchunks = (N + 63) / 64;
    k_gru<<<nchunks, 256, 0, stream>>>(ids, emb, ts, mem, lut, Wt, bt, bih, bhh,
                                       bfragH, bfragL, winner, out0, out1, N);

    long vec = (long)NUM_NODES * 16;
    k_tail<<<(int)((vec + 255) / 256), 256, 0, stream>>>(
        out2, (const f32x4*)mem, (f32x4*)out1, ts, lut, NUM_NODES);
}

// Round 13
// 226.784 us; speedup vs baseline: 1.8675x; 1.0135x over previous
//
#include <hip/hip_runtime.h>
#include <cstdint>
#include <cstddef>

#define DD 64

typedef float    f32x4  __attribute__((ext_vector_type(4)));
typedef _Float16 f16x8  __attribute__((ext_vector_type(8)));
typedef _Float16 f16x4  __attribute__((ext_vector_type(4)));

__device__ __forceinline__ float sigmoidf_(float x) {
    return 1.0f / (1.0f + __expf(-x));
}
__device__ __forceinline__ float tanh_fast(float x) {
    float ax = fabsf(x);
    float t = 1.0f - 2.0f / (1.0f + __expf(2.0f * ax));
    return copysignf(t, x);
}
__device__ __forceinline__ f32x4 MFMA(f32x4 c, f16x8 a, f16x8 b) {
    return __builtin_amdgcn_mfma_f32_16x16x32_f16(a, b, c, 0, 0, 0);
}

// ---------------- fused: B-fragment build (blocks 0..15) + winner init ----------------
// B[128][256]: cols 0..63 r (K: x|h), 64..127 z, 128..191 i_n (x), 192..255 h_n (h).
// Fragment f = g*4+s; lane l holds B[s*32+(l>>4)*8+j][g*16+(l&15)], j=0..7.
__global__ void k_prep_init(const float* __restrict__ Wih, const float* __restrict__ Whh,
                            _Float16* __restrict__ bhi, _Float16* __restrict__ blo,
                            int* __restrict__ winner, int num_nodes)
{
    if (blockIdx.x < 16) {
        int f = blockIdx.x * 4 + (threadIdx.x >> 6);   // 0..63
        int l = threadIdx.x & 63;
        int g = f >> 2, s = f & 3;
        int c = g * 16 + (l & 15);
        int grp = c >> 6, dd = c & 63;
        int kbase = s * 32 + (l >> 4) * 8;
        int row = (grp == 0) ? dd : (grp == 1) ? 64 + dd : 128 + dd;

        f16x8 hv, lv;
        for (int j = 0; j < 8; ++j) {
            int k = kbase + j;
            float v;
            if (grp <= 1)      v = (k < 64) ? Wih[row * 64 + k] : Whh[row * 64 + (k - 64)];
            else if (grp == 2) v = (k < 64) ? Wih[row * 64 + k] : 0.0f;
            else               v = (k < 64) ? 0.0f : Whh[row * 64 + (k - 64)];
            _Float16 h = (_Float16)v;
            hv[j] = h;
            lv[j] = (_Float16)(v - (float)h);
        }
        size_t off = ((size_t)f * 64 + l);
        ((f16x8*)bhi)[off] = hv;
        ((f16x8*)blo)[off] = lv;
    } else {
        int i = (int)(blockIdx.x - 16) * 256 + threadIdx.x;
        if (i < num_nodes) winner[i] = -1;
    }
}

// ---------------- vote + dt precompute ----------------
// atomicMax and lut gather are independent -> both in flight; dtw write coalesced.
// Hoists the lut random gather OFF k_gru's critical path (it fed CONV pre-barrier).
__global__ void k_vote_dt(const int* __restrict__ ids, const float* __restrict__ ts,
                          const float* __restrict__ lut, int* __restrict__ winner,
                          float* __restrict__ dtw, int n) {
    int i = blockIdx.x * blockDim.x + threadIdx.x;
    if (i < n) {
        int id = ids[i];
        atomicMax(&winner[id], i);
        dtw[i] = ts[i] - lut[id];
    }
}

// ---------------- main GRU kernel (MFMA, asymmetric split-fp16) ----------------
// r12 structure; single change: dt comes from precomputed dtw (coalesced) instead of
// the lut[id] random gather. winner gather kept (consumed in epilogue, off crit path).
__global__ __launch_bounds__(256, 4) void k_gru(
    const int* __restrict__ ids,
    const float* __restrict__ emb,
    const float* __restrict__ mem,
    const float* __restrict__ Wt,
    const float* __restrict__ bt,
    const float* __restrict__ bih,
    const float* __restrict__ bhh,
    const _Float16* __restrict__ bhi,
    const _Float16* __restrict__ blo,
    const int* __restrict__ winner,
    const float* __restrict__ dtw,
    float* __restrict__ out0,
    float* __restrict__ out1,
    int n)
{
    __shared__ _Float16 xhh[64][136];   // hi plane: [event][k], k<64 x_hi, k>=64 h
    __shared__ _Float16 xhl[64][72];    // lo plane: x_lo only (k<64)
    __shared__ int sid[64];
    __shared__ int swin[64];

    const int w    = threadIdx.x >> 6;
    const int l    = threadIdx.x & 63;
    const int col  = l & 15;
    const int rowg = l >> 4;
    const int d    = w * 16 + col;      // output dim this lane owns in epilogue

    const long base = (long)blockIdx.x * 64;
    const bool full = (base + 64 <= (long)n);

    // ---- phase A: coalesced ids + dtw; winner gather issues here, used in epilogue ----
    const int  e16 = w * 16 + col;
    const long evA = base + e16;
    int idA = 0, winA = 0; float dtA = 0.f;
    if (full || evA < n) {
        idA  = ids[evA];
        dtA  = dtw[evA];
        winA = (winner[idA] == (int)evA) ? 1 : 0;
    }
    if (l < 16) { sid[e16] = idA; swin[e16] = winA; }

    // ---- phase B load pass: issue all 8 global 16B loads back-to-back ----
    f32x4 xv0, xv1, xv2, xv3, hv0, hv1, hv2, hv3;
    float dt0, dt1, dt2, dt3;
    {
        int   i0 = __shfl(idA, 0 * 4 + rowg), i1 = __shfl(idA, 1 * 4 + rowg);
        int   i2 = __shfl(idA, 2 * 4 + rowg), i3 = __shfl(idA, 3 * 4 + rowg);
        dt0 = __shfl(dtA, 0 * 4 + rowg); dt1 = __shfl(dtA, 1 * 4 + rowg);
        dt2 = __shfl(dtA, 2 * 4 + rowg); dt3 = __shfl(dtA, 3 * 4 + rowg);
        const f32x4* emb4 = (const f32x4*)emb;
        const f32x4* mem4 = (const f32x4*)mem;
        const size_t e0 = (size_t)(base + w * 16 + 0 * 4 + rowg) * 16 + col;
        const size_t e1 = (size_t)(base + w * 16 + 1 * 4 + rowg) * 16 + col;
        const size_t e2 = (size_t)(base + w * 16 + 2 * 4 + rowg) * 16 + col;
        const size_t e3 = (size_t)(base + w * 16 + 3 * 4 + rowg) * 16 + col;
        if (full) {
            xv0 = __builtin_nontemporal_load(&emb4[e0]);
            xv1 = __builtin_nontemporal_load(&emb4[e1]);
            xv2 = __builtin_nontemporal_load(&emb4[e2]);
            xv3 = __builtin_nontemporal_load(&emb4[e3]);
            hv0 = mem4[(size_t)i0 * 16 + col];
            hv1 = mem4[(size_t)i1 * 16 + col];
            hv2 = mem4[(size_t)i2 * 16 + col];
            hv3 = mem4[(size_t)i3 * 16 + col];
        } else {
            f32x4 z = {0.f, 0.f, 0.f, 0.f};
            xv0 = xv1 = xv2 = xv3 = hv0 = hv1 = hv2 = hv3 = z;
            if (base + w * 16 + 0 * 4 + rowg < n) { xv0 = emb4[e0]; hv0 = mem4[(size_t)i0 * 16 + col]; }
            if (base + w * 16 + 1 * 4 + rowg < n) { xv1 = emb4[e1]; hv1 = mem4[(size_t)i1 * 16 + col]; }
            if (base + w * 16 + 2 * 4 + rowg < n) { xv2 = emb4[e2]; hv2 = mem4[(size_t)i2 * 16 + col]; }
            if (base + w * 16 + 3 * 4 + rowg < n) { xv3 = emb4[e3]; hv3 = mem4[(size_t)i3 * 16 + col]; }
        }
    }

    // ---- phase B convert/write pass ----
    const f32x4 wt4 = ((const f32x4*)Wt)[col];
    const f32x4 bt4 = ((const f32x4*)bt)[col];
    {
        #define CONV_WRITE(XV, HV, DT, IT)                                           \
        {                                                                            \
            int r = w * 16 + (IT) * 4 + rowg;                                        \
            f32x4 x = XV;                                                            \
            x.x = fmaf(DT, wt4.x, x.x + bt4.x);                                      \
            x.y = fmaf(DT, wt4.y, x.y + bt4.y);                                      \
            x.z = fmaf(DT, wt4.z, x.z + bt4.z);                                      \
            x.w = fmaf(DT, wt4.w, x.w + bt4.w);                                      \
            f16x4 xh, xl, hh;                                                        \
            _Float16 a;                                                              \
            a = (_Float16)x.x; xh[0] = a; xl[0] = (_Float16)(x.x - (float)a);        \
            a = (_Float16)x.y; xh[1] = a; xl[1] = (_Float16)(x.y - (float)a);        \
            a = (_Float16)x.z; xh[2] = a; xl[2] = (_Float16)(x.z - (float)a);        \
            a = (_Float16)x.w; xh[3] = a; xl[3] = (_Float16)(x.w - (float)a);        \
            hh[0] = (_Float16)(HV).x; hh[1] = (_Float16)(HV).y;                      \
            hh[2] = (_Float16)(HV).z; hh[3] = (_Float16)(HV).w;                      \
            *(f16x4*)&xhh[r][col * 4]      = xh;                                     \
            *(f16x4*)&xhl[r][col * 4]      = xl;                                     \
            *(f16x4*)&xhh[r][64 + col * 4] = hh;                                     \
        }
        CONV_WRITE(xv0, hv0, dt0, 0)
        CONV_WRITE(xv1, hv1, dt1, 1)
        CONV_WRITE(xv2, hv2, dt2, 2)
        CONV_WRITE(xv3, hv3, dt3, 3)
        #undef CONV_WRITE
    }

    // persistent B fragments for this wave's 4 gate tiles (L2-resident)
    const f16x8* H = (const f16x8*)bhi;
    const f16x8* L = (const f16x8*)blo;
    f16x8 BRh0 = H[(size_t)(w * 4 + 0) * 64 + l];
    f16x8 BRh1 = H[(size_t)(w * 4 + 1) * 64 + l];
    f16x8 BRh2 = H[(size_t)(w * 4 + 2) * 64 + l];
    f16x8 BRh3 = H[(size_t)(w * 4 + 3) * 64 + l];
    f16x8 BRl0 = L[(size_t)(w * 4 + 0) * 64 + l];
    f16x8 BRl1 = L[(size_t)(w * 4 + 1) * 64 + l];
    f16x8 BZh0 = H[(size_t)((4 + w) * 4 + 0) * 64 + l];
    f16x8 BZh1 = H[(size_t)((4 + w) * 4 + 1) * 64 + l];
    f16x8 BZh2 = H[(size_t)((4 + w) * 4 + 2) * 64 + l];
    f16x8 BZh3 = H[(size_t)((4 + w) * 4 + 3) * 64 + l];
    f16x8 BZl0 = L[(size_t)((4 + w) * 4 + 0) * 64 + l];
    f16x8 BZl1 = L[(size_t)((4 + w) * 4 + 1) * 64 + l];
    f16x8 BIh0 = H[(size_t)((8 + w) * 4 + 0) * 64 + l];
    f16x8 BIh1 = H[(size_t)((8 + w) * 4 + 1) * 64 + l];
    f16x8 BIl0 = L[(size_t)((8 + w) * 4 + 0) * 64 + l];
    f16x8 BIl1 = L[(size_t)((8 + w) * 4 + 1) * 64 + l];
    f16x8 BHh0 = H[(size_t)((12 + w) * 4 + 2) * 64 + l];
    f16x8 BHh1 = H[(size_t)((12 + w) * 4 + 3) * 64 + l];

    const float bR  = bih[d] + bhh[d];
    const float bZ  = bih[64 + d] + bhh[64 + d];
    const float bIN = bih[128 + d];
    const float bHN = bhh[128 + d];

    __syncthreads();

    // ---- 4 M-tiles of 16 events each ----
    #pragma unroll
    for (int mt = 0; mt < 4; ++mt) {
        const int arow = mt * 16 + col;
        const int k0   = rowg * 8;
        f16x8 Ah0 = *(const f16x8*)&xhh[arow][0 * 32 + k0];
        f16x8 Ah1 = *(const f16x8*)&xhh[arow][1 * 32 + k0];
        f16x8 Ah2 = *(const f16x8*)&xhh[arow][2 * 32 + k0];
        f16x8 Ah3 = *(const f16x8*)&xhh[arow][3 * 32 + k0];
        f16x8 Al0 = *(const f16x8*)&xhl[arow][0 * 32 + k0];
        f16x8 Al1 = *(const f16x8*)&xhl[arow][1 * 32 + k0];

        f32x4 aR = {0,0,0,0}, aZ = {0,0,0,0}, aI = {0,0,0,0}, aH = {0,0,0,0};
        __builtin_amdgcn_s_setprio(1);
        aR = MFMA(aR, Ah0, BRh0); aR = MFMA(aR, Ah0, BRl0); aR = MFMA(aR, Al0, BRh0);
        aR = MFMA(aR, Ah1, BRh1); aR = MFMA(aR, Ah1, BRl1); aR = MFMA(aR, Al1, BRh1);
        aR = MFMA(aR, Ah2, BRh2); aR = MFMA(aR, Ah3, BRh3);
        aZ = MFMA(aZ, Ah0, BZh0); aZ = MFMA(aZ, Ah0, BZl0); aZ = MFMA(aZ, Al0, BZh0);
        aZ = MFMA(aZ, Ah1, BZh1); aZ = MFMA(aZ, Ah1, BZl1); aZ = MFMA(aZ, Al1, BZh1);
        aZ = MFMA(aZ, Ah2, BZh2); aZ = MFMA(aZ, Ah3, BZh3);
        aI = MFMA(aI, Ah0, BIh0); aI = MFMA(aI, Ah0, BIl0); aI = MFMA(aI, Al0, BIh0);
        aI = MFMA(aI, Ah1, BIh1); aI = MFMA(aI, Ah1, BIl1); aI = MFMA(aI, Al1, BIh1);
        aH = MFMA(aH, Ah2, BHh0); aH = MFMA(aH, Ah3, BHh1);
        __builtin_amdgcn_s_setprio(0);

        #pragma unroll
        for (int r = 0; r < 4; ++r) {
            int  eloc = mt * 16 + rowg * 4 + r;
            long ev   = base + eloc;
            if (full || ev < n) {
                float rr = sigmoidf_(aR[r] + bR);
                float zz = sigmoidf_(aZ[r] + bZ);
                float nn = tanh_fast(aI[r] + bIN + rr * (aH[r] + bHN));
                float hv = (float)xhh[eloc][64 + d];
                float o  = (1.f - zz) * nn + zz * hv;
                out0[(size_t)ev * 64 + d] = o;
                if (swin[eloc])
                    out1[(size_t)sid[eloc] * 64 + d] = o;
            }
        }
    }
}

// ---------------- fused tail: loser-row copy + timestamp scatter ----------------
// winner stored IN out2; each 16-thread group reads its node's winner, then lane
// c==0 overwrites that same slot (read-before-write within the wave -> safe).
__global__ void k_tail(float* out2,
                       const f32x4* __restrict__ mem4,
                       f32x4* __restrict__ out14,
                       const float* __restrict__ ts,
                       const float* __restrict__ lut,
                       int num_nodes)
{
    int idx = blockIdx.x * blockDim.x + threadIdx.x;
    if (idx >= num_nodes * 16) return;
    int nidx = idx >> 4;
    int c    = idx & 15;
    int wv = reinterpret_cast<const int*>(out2)[nidx];
    if (wv < 0) {
        f32x4 v = __builtin_nontemporal_load(&mem4[idx]);
        __builtin_nontemporal_store(v, &out14[idx]);
    }
    if (c == 0) out2[nidx] = (wv >= 0) ? ts[wv] : lut[nidx];
}

extern "C" void kernel_launch(void* const* d_in, const int* in_sizes, int n_in,
                              void* d_out, int out_size, void* d_ws, size_t ws_size,
                              hipStream_t stream) {
    const int*   ids = (const int*)  d_in[0];
    const float* emb = (const float*)d_in[1];
    const float* ts  = (const float*)d_in[2];
    const float* mem = (const float*)d_in[3];
    const float* lut = (const float*)d_in[4];
    const float* Wt  = (const float*)d_in[5];
    const float* bt  = (const float*)d_in[6];
    const float* Wih = (const float*)d_in[7];
    const float* Whh = (const float*)d_in[8];
    const float* bih = (const float*)d_in[9];
    const float* bhh = (const float*)d_in[10];

    const int N         = in_sizes[0];
    const int NUM_NODES = in_sizes[4];

    float* out0 = (float*)d_out;                    // [N,64]
    float* out1 = out0 + (size_t)N * DD;            // [NUM_NODES,64]
    float* out2 = out1 + (size_t)NUM_NODES * DD;    // [NUM_NODES]
    int*   winner = (int*)out2;

    _Float16* bfragH = (_Float16*)d_ws;                      // 64 KB
    _Float16* bfragL = bfragH + 64 * 64 * 8;                 // 64 KB
    float*    dtw    = (float*)((char*)d_ws + 128 * 1024);   // N * 4 B (~2 MB)

    int initBlocks = (NUM_NODES + 255) / 256;
    k_prep_init<<<16 + initBlocks, 256, 0, stream>>>(Wih, Whh, bfragH, bfragL,
                                                     winner, NUM_NODES);
    k_vote_dt<<<(N + 255) / 256, 256, 0, stream>>>(ids, ts, lut, winner, dtw, N);

    int nchunks = (N + 63) / 64;
    k_gru<<<nchunks, 256, 0, stream>>>(ids, emb, mem, Wt, bt, bih, bhh,
                                       bfragH, bfragL, winner, dtw, out0, out1, N);

    long vec = (long)NUM_NODES * 16;
    k_tail<<<(int)((vec + 255) / 256), 256, 0, stream>>>(
        out2, (const f32x4*)mem, (f32x4*)out1, ts, lut, NUM_NODES);
}